// Round 1
// baseline (2123.792 us; speedup 1.0000x reference)
//
#include <hip/hip_runtime.h>
#include <math.h>

#define N_NODES 4096
#define E_EDGE 65536
#define D 512
#define NEXP 4
#define DSTATE 16
#define DCONV 4
#define DTRANK 32
#define EPS 1e-5f
#define LCHUNK 32
#define NCHUNK (N_NODES / LCHUNK)

__device__ __forceinline__ float siluf(float x) { return x / (1.f + __expf(-x)); }
__device__ __forceinline__ float softplusf(float x) {
  return (x > 20.f) ? x : log1pf(__expf(x));
}

// ---------------- edge aggregation: aggr[dst] += relu(x[src] + ea) --------
__global__ void edge_aggr_k(const float* __restrict__ x, const int* __restrict__ ei,
                            const float* __restrict__ ea, float* __restrict__ aggr) {
  int e = blockIdx.x;
  int src = ei[e];
  int dst = ei[E_EDGE + e];
  for (int d = threadIdx.x; d < D; d += blockDim.x) {
    float v = x[(size_t)src * D + d] + ea[(size_t)e * D + d];
    v = fmaxf(v, 0.f);
    atomicAdd(&aggr[(size_t)dst * D + d], v);
  }
}

// ---------------- elementwise add ----------------------------------------
__global__ void add_k(const float* __restrict__ a, const float* __restrict__ b,
                      float* __restrict__ o, int n) {
  int i = blockIdx.x * blockDim.x + threadIdx.x;
  if (i < n) o[i] = a[i] + b[i];
}

// ---------------- generic tiled fp32 GEMM --------------------------------
// C(MxN) = op(A(MxK) @ B(KxN)); requires M%64==0, N%64==0, K%16==0.
// MODE 0: C = A@B (+bias)        MODE 1: relu(A@B + bias)
// MODE 2: C += rowscale[m*rs]* (A@B)   MODE 3: softplus(A@B + bias)
template <int MODE>
__global__ __launch_bounds__(256) void gemm_k(
    const float* __restrict__ A, int lda, const float* __restrict__ B, int ldb,
    const float* __restrict__ bias, float* __restrict__ C, int ldc,
    const float* __restrict__ rowscale, int rs_stride, int M, int N, int K) {
  __shared__ float As[16][65];
  __shared__ float Bs[16][65];
  const int bm = blockIdx.y * 64;
  const int bn = blockIdx.x * 64;
  const int tid = threadIdx.x;
  const int tr = (tid >> 4) << 2;
  const int tc = (tid & 15) << 2;
  float acc[4][4] = {};
  for (int k0 = 0; k0 < K; k0 += 16) {
#pragma unroll
    for (int i = 0; i < 4; ++i) {
      int idx = tid + i * 256;
      int mm = idx >> 4, kk = idx & 15;
      As[kk][mm] = A[(size_t)(bm + mm) * lda + k0 + kk];
    }
#pragma unroll
    for (int i = 0; i < 4; ++i) {
      int idx = tid + i * 256;
      int kk = idx >> 6, nn = idx & 63;
      Bs[kk][nn] = B[(size_t)(k0 + kk) * ldb + bn + nn];
    }
    __syncthreads();
#pragma unroll
    for (int kk = 0; kk < 16; ++kk) {
      float a[4], b[4];
#pragma unroll
      for (int i = 0; i < 4; ++i) a[i] = As[kk][tr + i];
#pragma unroll
      for (int j = 0; j < 4; ++j) b[j] = Bs[kk][tc + j];
#pragma unroll
      for (int i = 0; i < 4; ++i)
#pragma unroll
        for (int j = 0; j < 4; ++j) acc[i][j] = fmaf(a[i], b[j], acc[i][j]);
    }
    __syncthreads();
  }
#pragma unroll
  for (int i = 0; i < 4; ++i) {
    int row = bm + tr + i;
#pragma unroll
    for (int j = 0; j < 4; ++j) {
      int col = bn + tc + j;
      float v = acc[i][j];
      if (MODE == 2) {
        C[(size_t)row * ldc + col] += rowscale[(size_t)row * rs_stride] * v;
      } else {
        if (bias) v += bias[col];
        if (MODE == 1) v = fmaxf(v, 0.f);
        if (MODE == 3) v = softplusf(v);
        C[(size_t)row * ldc + col] = v;
      }
    }
  }
}

// ---------------- gate second layer + softmax (N -> 4) --------------------
__global__ __launch_bounds__(256) void gate2_k(const float* __restrict__ g1,
                                               const float* __restrict__ w2,
                                               const float* __restrict__ b2,
                                               float* __restrict__ gate) {
  int row = blockIdx.x * 4 + (threadIdx.x >> 6);
  int lane = threadIdx.x & 63;
  float a0 = 0.f, a1 = 0.f, a2 = 0.f, a3 = 0.f;
  for (int k = lane; k < 256; k += 64) {
    float v = g1[(size_t)row * 256 + k];
    a0 = fmaf(v, w2[k * 4 + 0], a0);
    a1 = fmaf(v, w2[k * 4 + 1], a1);
    a2 = fmaf(v, w2[k * 4 + 2], a2);
    a3 = fmaf(v, w2[k * 4 + 3], a3);
  }
#pragma unroll
  for (int off = 32; off; off >>= 1) {
    a0 += __shfl_down(a0, off);
    a1 += __shfl_down(a1, off);
    a2 += __shfl_down(a2, off);
    a3 += __shfl_down(a3, off);
  }
  if (lane == 0) {
    float l0 = a0 + b2[0], l1 = a1 + b2[1], l2 = a2 + b2[2], l3 = a3 + b2[3];
    float m = fmaxf(fmaxf(l0, l1), fmaxf(l2, l3));
    float e0 = __expf(l0 - m), e1 = __expf(l1 - m), e2 = __expf(l2 - m), e3 = __expf(l3 - m);
    float s = 1.f / (e0 + e1 + e2 + e3);
    gate[row * 4 + 0] = e0 * s;
    gate[row * 4 + 1] = e1 * s;
    gate[row * 4 + 2] = e2 * s;
    gate[row * 4 + 3] = e3 * s;
  }
}

// ---------------- causal depthwise conv + silu ----------------------------
__global__ void conv_silu_k(const float* __restrict__ xz, const float* __restrict__ cw,
                            const float* __restrict__ cb, float* __restrict__ xs) {
  int idx = blockIdx.x * blockDim.x + threadIdx.x;
  if (idx >= N_NODES * D) return;
  int t = idx >> 9;
  int d = idx & (D - 1);
  float acc = cb[d];
#pragma unroll
  for (int k = 0; k < DCONV; ++k) {
    int tt = t + k - (DCONV - 1);
    if (tt >= 0) acc = fmaf(cw[d * DCONV + k], xz[(size_t)tt * (2 * D) + d], acc);
  }
  xs[idx] = siluf(acc);
}

// ---------------- BN stats: one block per column --------------------------
__global__ __launch_bounds__(256) void bn_stats_k(const float* __restrict__ p,
                                                  const float* __restrict__ q,
                                                  float* __restrict__ mu,
                                                  float* __restrict__ rsig) {
  int d = blockIdx.x;
  float s = 0.f, s2 = 0.f;
  for (int r = threadIdx.x; r < N_NODES; r += 256) {
    float v = p[(size_t)r * D + d] + q[(size_t)r * D + d];
    s += v;
    s2 = fmaf(v, v, s2);
  }
  __shared__ float sh[256], sh2[256];
  sh[threadIdx.x] = s;
  sh2[threadIdx.x] = s2;
  __syncthreads();
  for (int off = 128; off; off >>= 1) {
    if (threadIdx.x < off) {
      sh[threadIdx.x] += sh[threadIdx.x + off];
      sh2[threadIdx.x] += sh2[threadIdx.x + off];
    }
    __syncthreads();
  }
  if (threadIdx.x == 0) {
    float m = sh[0] / N_NODES;
    float var = sh2[0] / N_NODES - m * m;
    mu[d] = m;
    rsig[d] = rsqrtf(var + EPS);
  }
}

__global__ void bn_norm_k(const float* __restrict__ p, const float* __restrict__ q,
                          const float* __restrict__ mu, const float* __restrict__ rsig,
                          const float* __restrict__ g, const float* __restrict__ b,
                          float* __restrict__ o) {
  int idx = blockIdx.x * blockDim.x + threadIdx.x;
  if (idx >= N_NODES * D) return;
  int d = idx & (D - 1);
  o[idx] = (p[idx] + q[idx] - mu[d]) * rsig[d] * g[d] + b[d];
}

// ---------------- chunked selective scan ----------------------------------
// Phase A: per-(chunk,d) local scan from h=0 -> Q (chunk-end state), dtsum.
__global__ __launch_bounds__(512) void scanA_k(const float* __restrict__ dt,
                                               const float* __restrict__ xs,
                                               const float* __restrict__ dbc,
                                               const float* __restrict__ Alog,
                                               float* __restrict__ Q,
                                               float* __restrict__ dtsum) {
  int c = blockIdx.x;
  int d = threadIdx.x;
  float As[DSTATE], h[DSTATE];
#pragma unroll
  for (int s = 0; s < DSTATE; ++s) {
    As[s] = -__expf(Alog[d * DSTATE + s]);
    h[s] = 0.f;
  }
  float dts = 0.f;
  int t0 = c * LCHUNK;
  for (int t = t0; t < t0 + LCHUNK; ++t) {
    float dtv = dt[(size_t)t * D + d];
    float xv = xs[(size_t)t * D + d];
    float bx = dtv * xv;
    dts += dtv;
#pragma unroll
    for (int s = 0; s < DSTATE; ++s) {
      float Bv = dbc[(size_t)t * 64 + DTRANK + s];
      h[s] = fmaf(__expf(dtv * As[s]), h[s], bx * Bv);
    }
  }
  size_t base = ((size_t)c * D + d) * DSTATE;
#pragma unroll
  for (int s = 0; s < DSTATE; ++s) Q[base + s] = h[s];
  dtsum[c * D + d] = dts;
}

// Phase B: serial over chunks (cheap): Hin[c] = state entering chunk c.
__global__ void scanB_k(const float* __restrict__ Q, const float* __restrict__ dtsum,
                        const float* __restrict__ Alog, float* __restrict__ Hin) {
  int d = blockIdx.x * blockDim.x + threadIdx.x;
  if (d >= D) return;
  float As[DSTATE], h[DSTATE];
#pragma unroll
  for (int s = 0; s < DSTATE; ++s) {
    As[s] = -__expf(Alog[d * DSTATE + s]);
    h[s] = 0.f;
  }
  for (int c = 0; c < NCHUNK; ++c) {
    size_t base = ((size_t)c * D + d) * DSTATE;
    float dts = dtsum[c * D + d];
#pragma unroll
    for (int s = 0; s < DSTATE; ++s) {
      Hin[base + s] = h[s];
      h[s] = fmaf(__expf(As[s] * dts), h[s], Q[base + s]);
    }
  }
}

// Phase C: replay chunk with true initial state, emit u = (y + Dp*xs)*silu(z)
__global__ __launch_bounds__(512) void scanC_k(const float* __restrict__ dt,
                                               const float* __restrict__ xs,
                                               const float* __restrict__ dbc,
                                               const float* __restrict__ Alog,
                                               const float* __restrict__ Hin,
                                               const float* __restrict__ xz,
                                               const float* __restrict__ Dp,
                                               float* __restrict__ u) {
  int c = blockIdx.x;
  int d = threadIdx.x;
  float As[DSTATE], h[DSTATE];
  size_t base = ((size_t)c * D + d) * DSTATE;
#pragma unroll
  for (int s = 0; s < DSTATE; ++s) {
    As[s] = -__expf(Alog[d * DSTATE + s]);
    h[s] = Hin[base + s];
  }
  float Dv = Dp[d];
  int t0 = c * LCHUNK;
  for (int t = t0; t < t0 + LCHUNK; ++t) {
    float dtv = dt[(size_t)t * D + d];
    float xv = xs[(size_t)t * D + d];
    float bx = dtv * xv;
    float y = 0.f;
#pragma unroll
    for (int s = 0; s < DSTATE; ++s) {
      float Bv = dbc[(size_t)t * 64 + DTRANK + s];
      float Cv = dbc[(size_t)t * 64 + DTRANK + DSTATE + s];
      h[s] = fmaf(__expf(dtv * As[s]), h[s], bx * Bv);
      y = fmaf(h[s], Cv, y);
    }
    float z = xz[(size_t)t * (2 * D) + D + d];
    u[(size_t)t * D + d] = (y + Dv * xv) * siluf(z);
  }
}

extern "C" void kernel_launch(void* const* d_in, const int* in_sizes, int n_in,
                              void* d_out, int out_size, void* d_ws, size_t ws_size,
                              hipStream_t stream) {
  const float* x = (const float*)d_in[0];
  const int* ei = (const int*)d_in[1];
  const float* ea = (const float*)d_in[2];
  const float* gin_w1 = (const float*)d_in[3];
  const float* gin_b1 = (const float*)d_in[4];
  const float* gin_w2 = (const float*)d_in[5];
  const float* gin_b2 = (const float*)d_in[6];
  const float* bn1l_g = (const float*)d_in[7];
  const float* bn1l_b = (const float*)d_in[8];
  const float* bn1a_g = (const float*)d_in[9];
  const float* bn1a_b = (const float*)d_in[10];
  const float* bn2_g = (const float*)d_in[11];
  const float* bn2_b = (const float*)d_in[12];
  const float* gate_w1 = (const float*)d_in[13];
  const float* gate_b1 = (const float*)d_in[14];
  const float* gate_w2 = (const float*)d_in[15];
  const float* gate_b2 = (const float*)d_in[16];
  const float* in_w = (const float*)d_in[17];
  const float* conv_w = (const float*)d_in[18];
  const float* conv_b = (const float*)d_in[19];
  const float* x_w = (const float*)d_in[20];
  const float* dt_w = (const float*)d_in[21];
  const float* dt_b = (const float*)d_in[22];
  const float* A_log = (const float*)d_in[23];
  const float* Dp = (const float*)d_in[24];
  const float* out_w = (const float*)d_in[25];
  const float* ff_w1 = (const float*)d_in[26];
  const float* ff_b1 = (const float*)d_in[27];
  const float* ff_w2 = (const float*)d_in[28];
  const float* ff_b2 = (const float*)d_in[29];
  float* out = (float*)d_out;

  const size_t ND = (size_t)N_NODES * D;  // 2M floats
  float* ws = (float*)d_ws;
  size_t o = 0;
  auto alloc = [&](size_t n) { float* p = ws + o; o += n; return p; };
  float* aggr = alloc(ND);                       // hpre (in place)
  float* t1 = alloc(ND);                         // gin hidden; later h
  float* hlocal = alloc(ND);                     // gin out -> bn1l (in place)
  float* g1 = alloc((size_t)N_NODES * 256);      // gate hidden
  float* gate = alloc((size_t)N_NODES * NEXP);   // softmax gate
  float* xz = alloc(ND * 2);                     // in_proj out; later ff hidden
  float* xs = alloc(ND);                         // conv+silu; later ff out
  float* dbc = alloc((size_t)N_NODES * 64);      // xs @ x_w
  float* dtb = alloc(ND);                        // softplus dt
  float* Qb = alloc((size_t)NCHUNK * D * DSTATE);
  float* Hin = alloc((size_t)NCHUNK * D * DSTATE);
  float* dtsum = alloc((size_t)NCHUNK * D);
  float* ubuf = alloc(ND);                       // (y+Dp*xs)*silu(z)
  float* hattn = alloc(ND);                      // expert-weighted sum (accum)
  float* mu = alloc(D);
  float* rsig = alloc(D);
  (void)o;  // ~21.3M floats = ~86 MB

  const int nelem = N_NODES * D;
  const int ew_blocks = (nelem + 255) / 256;

  hipMemsetAsync(aggr, 0, ND * sizeof(float), stream);
  hipMemsetAsync(hattn, 0, ND * sizeof(float), stream);

  // ---- GIN local branch ----
  edge_aggr_k<<<E_EDGE, 256, 0, stream>>>(x, ei, ea, aggr);
  add_k<<<ew_blocks, 256, 0, stream>>>(x, aggr, aggr, nelem);
  gemm_k<1><<<dim3(D / 64, N_NODES / 64), 256, 0, stream>>>(
      aggr, D, gin_w1, D, gin_b1, t1, D, nullptr, 0, N_NODES, D, D);
  gemm_k<0><<<dim3(D / 64, N_NODES / 64), 256, 0, stream>>>(
      t1, D, gin_w2, D, gin_b2, hlocal, D, nullptr, 0, N_NODES, D, D);
  bn_stats_k<<<D, 256, 0, stream>>>(x, hlocal, mu, rsig);
  bn_norm_k<<<ew_blocks, 256, 0, stream>>>(x, hlocal, mu, rsig, bn1l_g, bn1l_b, hlocal);

  // ---- gate ----
  gemm_k<1><<<dim3(256 / 64, N_NODES / 64), 256, 0, stream>>>(
      x, D, gate_w1, 256, gate_b1, g1, 256, nullptr, 0, N_NODES, 256, D);
  gate2_k<<<N_NODES / 4, 256, 0, stream>>>(g1, gate_w2, gate_b2, gate);

  // ---- experts (sequential, shared buffers) ----
  for (int e = 0; e < NEXP; ++e) {
    gemm_k<0><<<dim3(2 * D / 64, N_NODES / 64), 256, 0, stream>>>(
        x, D, in_w + (size_t)e * D * 2 * D, 2 * D, nullptr, xz, 2 * D, nullptr, 0,
        N_NODES, 2 * D, D);
    conv_silu_k<<<ew_blocks, 256, 0, stream>>>(xz, conv_w + (size_t)e * D * DCONV,
                                               conv_b + (size_t)e * D, xs);
    gemm_k<0><<<dim3(1, N_NODES / 64), 256, 0, stream>>>(
        xs, D, x_w + (size_t)e * D * 64, 64, nullptr, dbc, 64, nullptr, 0,
        N_NODES, 64, D);
    gemm_k<3><<<dim3(D / 64, N_NODES / 64), 256, 0, stream>>>(
        dbc, 64, dt_w + (size_t)e * DTRANK * D, D, dt_b + (size_t)e * D, dtb, D,
        nullptr, 0, N_NODES, D, DTRANK);
    const float* Al = A_log + (size_t)e * D * DSTATE;
    scanA_k<<<NCHUNK, D, 0, stream>>>(dtb, xs, dbc, Al, Qb, dtsum);
    scanB_k<<<2, 256, 0, stream>>>(Qb, dtsum, Al, Hin);
    scanC_k<<<NCHUNK, D, 0, stream>>>(dtb, xs, dbc, Al, Hin, xz, Dp + (size_t)e * D, ubuf);
    gemm_k<2><<<dim3(D / 64, N_NODES / 64), 256, 0, stream>>>(
        ubuf, D, out_w + (size_t)e * D * D, D, nullptr, hattn, D, gate + e, NEXP,
        N_NODES, D, D);
  }

  // ---- attn BN, combine, FFN, final BN ----
  bn_stats_k<<<D, 256, 0, stream>>>(x, hattn, mu, rsig);
  bn_norm_k<<<ew_blocks, 256, 0, stream>>>(x, hattn, mu, rsig, bn1a_g, bn1a_b, hattn);
  add_k<<<ew_blocks, 256, 0, stream>>>(hlocal, hattn, t1, nelem);
  gemm_k<1><<<dim3(2 * D / 64, N_NODES / 64), 256, 0, stream>>>(
      t1, D, ff_w1, 2 * D, ff_b1, xz, 2 * D, nullptr, 0, N_NODES, 2 * D, D);
  gemm_k<0><<<dim3(D / 64, N_NODES / 64), 256, 0, stream>>>(
      xz, 2 * D, ff_w2, D, ff_b2, xs, D, nullptr, 0, N_NODES, D, 2 * D);
  bn_stats_k<<<D, 256, 0, stream>>>(t1, xs, mu, rsig);
  bn_norm_k<<<ew_blocks, 256, 0, stream>>>(t1, xs, mu, rsig, bn2_g, bn2_b, out);
}

// Round 2
// 1626.501 us; speedup vs baseline: 1.3057x; 1.3057x over previous
//
#include <hip/hip_runtime.h>
#include <math.h>

#define N_NODES 4096
#define E_EDGE 65536
#define D 512
#define NEXP 4
#define DSTATE 16
#define DCONV 4
#define DTRANK 32
#define EPS 1e-5f
#define LCHUNK 16
#define NCHUNK (N_NODES / LCHUNK)

__device__ __forceinline__ float siluf(float x) { return x / (1.f + __expf(-x)); }
__device__ __forceinline__ float softplusf(float x) {
  return (x > 20.f) ? x : log1pf(__expf(x));
}

// ---------------- edge aggregation: aggr[dst] += relu(x[src] + ea) --------
__global__ void edge_aggr_k(const float* __restrict__ x, const int* __restrict__ ei,
                            const float* __restrict__ ea, float* __restrict__ aggr) {
  int e = blockIdx.x;
  int src = ei[e];
  int dst = ei[E_EDGE + e];
  for (int d = threadIdx.x; d < D; d += blockDim.x) {
    float v = x[(size_t)src * D + d] + ea[(size_t)e * D + d];
    v = fmaxf(v, 0.f);
    atomicAdd(&aggr[(size_t)dst * D + d], v);
  }
}

// ---------------- elementwise add ----------------------------------------
__global__ void add_k(const float* __restrict__ a, const float* __restrict__ b,
                      float* __restrict__ o, int n) {
  int i = blockIdx.x * blockDim.x + threadIdx.x;
  if (i < n) o[i] = a[i] + b[i];
}

// ---------------- generic tiled fp32 GEMM --------------------------------
// C(MxN) = op(A(MxK) @ B(KxN)); requires M%64==0, N%64==0, K%16==0.
// MODE 0: C = A@B (+bias)        MODE 1: relu(A@B + bias)
// MODE 2: C += rowscale[m*rs]* (A@B)   MODE 3: softplus(A@B + bias)
template <int MODE>
__global__ __launch_bounds__(256) void gemm_k(
    const float* __restrict__ A, int lda, const float* __restrict__ B, int ldb,
    const float* __restrict__ bias, float* __restrict__ C, int ldc,
    const float* __restrict__ rowscale, int rs_stride, int M, int N, int K) {
  __shared__ float As[16][65];
  __shared__ float Bs[16][65];
  const int bm = blockIdx.y * 64;
  const int bn = blockIdx.x * 64;
  const int tid = threadIdx.x;
  const int tr = (tid >> 4) << 2;
  const int tc = (tid & 15) << 2;
  float acc[4][4] = {};
  for (int k0 = 0; k0 < K; k0 += 16) {
#pragma unroll
    for (int i = 0; i < 4; ++i) {
      int idx = tid + i * 256;
      int mm = idx >> 4, kk = idx & 15;
      As[kk][mm] = A[(size_t)(bm + mm) * lda + k0 + kk];
    }
#pragma unroll
    for (int i = 0; i < 4; ++i) {
      int idx = tid + i * 256;
      int kk = idx >> 6, nn = idx & 63;
      Bs[kk][nn] = B[(size_t)(k0 + kk) * ldb + bn + nn];
    }
    __syncthreads();
#pragma unroll
    for (int kk = 0; kk < 16; ++kk) {
      float a[4], b[4];
#pragma unroll
      for (int i = 0; i < 4; ++i) a[i] = As[kk][tr + i];
#pragma unroll
      for (int j = 0; j < 4; ++j) b[j] = Bs[kk][tc + j];
#pragma unroll
      for (int i = 0; i < 4; ++i)
#pragma unroll
        for (int j = 0; j < 4; ++j) acc[i][j] = fmaf(a[i], b[j], acc[i][j]);
    }
    __syncthreads();
  }
#pragma unroll
  for (int i = 0; i < 4; ++i) {
    int row = bm + tr + i;
#pragma unroll
    for (int j = 0; j < 4; ++j) {
      int col = bn + tc + j;
      float v = acc[i][j];
      if (MODE == 2) {
        C[(size_t)row * ldc + col] += rowscale[(size_t)row * rs_stride] * v;
      } else {
        if (bias) v += bias[col];
        if (MODE == 1) v = fmaxf(v, 0.f);
        if (MODE == 3) v = softplusf(v);
        C[(size_t)row * ldc + col] = v;
      }
    }
  }
}

// ---------------- gate second layer + softmax (N -> 4) --------------------
__global__ __launch_bounds__(256) void gate2_k(const float* __restrict__ g1,
                                               const float* __restrict__ w2,
                                               const float* __restrict__ b2,
                                               float* __restrict__ gate) {
  int row = blockIdx.x * 4 + (threadIdx.x >> 6);
  int lane = threadIdx.x & 63;
  float a0 = 0.f, a1 = 0.f, a2 = 0.f, a3 = 0.f;
  for (int k = lane; k < 256; k += 64) {
    float v = g1[(size_t)row * 256 + k];
    a0 = fmaf(v, w2[k * 4 + 0], a0);
    a1 = fmaf(v, w2[k * 4 + 1], a1);
    a2 = fmaf(v, w2[k * 4 + 2], a2);
    a3 = fmaf(v, w2[k * 4 + 3], a3);
  }
#pragma unroll
  for (int off = 32; off; off >>= 1) {
    a0 += __shfl_down(a0, off);
    a1 += __shfl_down(a1, off);
    a2 += __shfl_down(a2, off);
    a3 += __shfl_down(a3, off);
  }
  if (lane == 0) {
    float l0 = a0 + b2[0], l1 = a1 + b2[1], l2 = a2 + b2[2], l3 = a3 + b2[3];
    float m = fmaxf(fmaxf(l0, l1), fmaxf(l2, l3));
    float e0 = __expf(l0 - m), e1 = __expf(l1 - m), e2 = __expf(l2 - m), e3 = __expf(l3 - m);
    float s = 1.f / (e0 + e1 + e2 + e3);
    gate[row * 4 + 0] = e0 * s;
    gate[row * 4 + 1] = e1 * s;
    gate[row * 4 + 2] = e2 * s;
    gate[row * 4 + 3] = e3 * s;
  }
}

// ---------------- causal depthwise conv + silu ----------------------------
__global__ void conv_silu_k(const float* __restrict__ xz, const float* __restrict__ cw,
                            const float* __restrict__ cb, float* __restrict__ xs) {
  int idx = blockIdx.x * blockDim.x + threadIdx.x;
  if (idx >= N_NODES * D) return;
  int t = idx >> 9;
  int d = idx & (D - 1);
  float acc = cb[d];
#pragma unroll
  for (int k = 0; k < DCONV; ++k) {
    int tt = t + k - (DCONV - 1);
    if (tt >= 0) acc = fmaf(cw[d * DCONV + k], xz[(size_t)tt * (2 * D) + d], acc);
  }
  xs[idx] = siluf(acc);
}

// ---------------- BN stats: one block per column --------------------------
__global__ __launch_bounds__(256) void bn_stats_k(const float* __restrict__ p,
                                                  const float* __restrict__ q,
                                                  float* __restrict__ mu,
                                                  float* __restrict__ rsig) {
  int d = blockIdx.x;
  float s = 0.f, s2 = 0.f;
  for (int r = threadIdx.x; r < N_NODES; r += 256) {
    float v = p[(size_t)r * D + d] + q[(size_t)r * D + d];
    s += v;
    s2 = fmaf(v, v, s2);
  }
  __shared__ float sh[256], sh2[256];
  sh[threadIdx.x] = s;
  sh2[threadIdx.x] = s2;
  __syncthreads();
  for (int off = 128; off; off >>= 1) {
    if (threadIdx.x < off) {
      sh[threadIdx.x] += sh[threadIdx.x + off];
      sh2[threadIdx.x] += sh2[threadIdx.x + off];
    }
    __syncthreads();
  }
  if (threadIdx.x == 0) {
    float m = sh[0] / N_NODES;
    float var = sh2[0] / N_NODES - m * m;
    mu[d] = m;
    rsig[d] = rsqrtf(var + EPS);
  }
}

__global__ void bn_norm_k(const float* __restrict__ p, const float* __restrict__ q,
                          const float* __restrict__ mu, const float* __restrict__ rsig,
                          const float* __restrict__ g, const float* __restrict__ b,
                          float* __restrict__ o) {
  int idx = blockIdx.x * blockDim.x + threadIdx.x;
  if (idx >= N_NODES * D) return;
  int d = idx & (D - 1);
  o[idx] = (p[idx] + q[idx] - mu[d]) * rsig[d] * g[d] + b[d];
}

// ---------------- chunked selective scan ----------------------------------
// Phase A: per-(chunk,d) local scan from h=0 -> Q (chunk-end state), dtsum.
__global__ __launch_bounds__(512) void scanA_k(const float* __restrict__ dt,
                                               const float* __restrict__ xs,
                                               const float* __restrict__ dbc,
                                               const float* __restrict__ Alog,
                                               float* __restrict__ Q,
                                               float* __restrict__ dtsum) {
  int c = blockIdx.x;
  int d = threadIdx.x;
  float As[DSTATE], h[DSTATE];
#pragma unroll
  for (int s = 0; s < DSTATE; ++s) {
    As[s] = -__expf(Alog[d * DSTATE + s]);
    h[s] = 0.f;
  }
  float dts = 0.f;
  int t0 = c * LCHUNK;
  for (int t = t0; t < t0 + LCHUNK; ++t) {
    float dtv = dt[(size_t)t * D + d];
    float xv = xs[(size_t)t * D + d];
    float bx = dtv * xv;
    dts += dtv;
#pragma unroll
    for (int s = 0; s < DSTATE; ++s) {
      float Bv = dbc[(size_t)t * 64 + DTRANK + s];
      h[s] = fmaf(__expf(dtv * As[s]), h[s], bx * Bv);
    }
  }
  size_t base = ((size_t)c * D + d) * DSTATE;
#pragma unroll
  for (int s = 0; s < DSTATE; ++s) Q[base + s] = h[s];
  dtsum[c * D + d] = dts;
}

// Phase B: serial over chunks, parallel over (d,s): 8192 independent chains.
// Hin[c,d,s] = state entering chunk c for channel (d,s).
__global__ __launch_bounds__(256) void scanB_k(const float* __restrict__ Q,
                                               const float* __restrict__ dtsum,
                                               const float* __restrict__ Alog,
                                               float* __restrict__ Hin) {
  int idx = blockIdx.x * blockDim.x + threadIdx.x;  // d*DSTATE + s
  if (idx >= D * DSTATE) return;
  int d = idx >> 4;
  float As = -__expf(Alog[idx]);
  float h = 0.f;
  for (int c = 0; c < NCHUNK; ++c) {
    size_t base = (size_t)c * D * DSTATE + idx;
    Hin[base] = h;
    h = fmaf(__expf(As * dtsum[c * D + d]), h, Q[base]);
  }
}

// Phase C: replay chunk with true initial state, emit u = (y + Dp*xs)*silu(z)
__global__ __launch_bounds__(512) void scanC_k(const float* __restrict__ dt,
                                               const float* __restrict__ xs,
                                               const float* __restrict__ dbc,
                                               const float* __restrict__ Alog,
                                               const float* __restrict__ Hin,
                                               const float* __restrict__ xz,
                                               const float* __restrict__ Dp,
                                               float* __restrict__ u) {
  int c = blockIdx.x;
  int d = threadIdx.x;
  float As[DSTATE], h[DSTATE];
  size_t base = ((size_t)c * D + d) * DSTATE;
#pragma unroll
  for (int s = 0; s < DSTATE; ++s) {
    As[s] = -__expf(Alog[d * DSTATE + s]);
    h[s] = Hin[base + s];
  }
  float Dv = Dp[d];
  int t0 = c * LCHUNK;
  for (int t = t0; t < t0 + LCHUNK; ++t) {
    float dtv = dt[(size_t)t * D + d];
    float xv = xs[(size_t)t * D + d];
    float bx = dtv * xv;
    float y = 0.f;
#pragma unroll
    for (int s = 0; s < DSTATE; ++s) {
      float Bv = dbc[(size_t)t * 64 + DTRANK + s];
      float Cv = dbc[(size_t)t * 64 + DTRANK + DSTATE + s];
      h[s] = fmaf(__expf(dtv * As[s]), h[s], bx * Bv);
      y = fmaf(h[s], Cv, y);
    }
    float z = xz[(size_t)t * (2 * D) + D + d];
    u[(size_t)t * D + d] = (y + Dv * xv) * siluf(z);
  }
}

extern "C" void kernel_launch(void* const* d_in, const int* in_sizes, int n_in,
                              void* d_out, int out_size, void* d_ws, size_t ws_size,
                              hipStream_t stream) {
  const float* x = (const float*)d_in[0];
  const int* ei = (const int*)d_in[1];
  const float* ea = (const float*)d_in[2];
  const float* gin_w1 = (const float*)d_in[3];
  const float* gin_b1 = (const float*)d_in[4];
  const float* gin_w2 = (const float*)d_in[5];
  const float* gin_b2 = (const float*)d_in[6];
  const float* bn1l_g = (const float*)d_in[7];
  const float* bn1l_b = (const float*)d_in[8];
  const float* bn1a_g = (const float*)d_in[9];
  const float* bn1a_b = (const float*)d_in[10];
  const float* bn2_g = (const float*)d_in[11];
  const float* bn2_b = (const float*)d_in[12];
  const float* gate_w1 = (const float*)d_in[13];
  const float* gate_b1 = (const float*)d_in[14];
  const float* gate_w2 = (const float*)d_in[15];
  const float* gate_b2 = (const float*)d_in[16];
  const float* in_w = (const float*)d_in[17];
  const float* conv_w = (const float*)d_in[18];
  const float* conv_b = (const float*)d_in[19];
  const float* x_w = (const float*)d_in[20];
  const float* dt_w = (const float*)d_in[21];
  const float* dt_b = (const float*)d_in[22];
  const float* A_log = (const float*)d_in[23];
  const float* Dp = (const float*)d_in[24];
  const float* out_w = (const float*)d_in[25];
  const float* ff_w1 = (const float*)d_in[26];
  const float* ff_b1 = (const float*)d_in[27];
  const float* ff_w2 = (const float*)d_in[28];
  const float* ff_b2 = (const float*)d_in[29];
  float* out = (float*)d_out;

  const size_t ND = (size_t)N_NODES * D;  // 2M floats
  float* ws = (float*)d_ws;
  size_t o = 0;
  auto alloc = [&](size_t n) { float* p = ws + o; o += n; return p; };
  float* aggr = alloc(ND);                       // hpre (in place)
  float* t1 = alloc(ND);                         // gin hidden; later h
  float* hlocal = alloc(ND);                     // gin out -> bn1l (in place)
  float* g1 = alloc((size_t)N_NODES * 256);      // gate hidden
  float* gate = alloc((size_t)N_NODES * NEXP);   // softmax gate
  float* xz = alloc(ND * 2);                     // in_proj out; later ff hidden
  float* xs = alloc(ND);                         // conv+silu; later ff out
  float* dbc = alloc((size_t)N_NODES * 64);      // xs @ x_w
  float* dtb = alloc(ND);                        // softplus dt
  float* Qb = alloc((size_t)NCHUNK * D * DSTATE);
  float* Hin = alloc((size_t)NCHUNK * D * DSTATE);
  float* dtsum = alloc((size_t)NCHUNK * D);
  float* ubuf = alloc(ND);                       // (y+Dp*xs)*silu(z)
  float* hattn = alloc(ND);                      // expert-weighted sum (accum)
  float* mu = alloc(D);
  float* rsig = alloc(D);
  (void)o;  // ~30M floats = ~120 MB

  const int nelem = N_NODES * D;
  const int ew_blocks = (nelem + 255) / 256;

  hipMemsetAsync(aggr, 0, ND * sizeof(float), stream);
  hipMemsetAsync(hattn, 0, ND * sizeof(float), stream);

  // ---- GIN local branch ----
  edge_aggr_k<<<E_EDGE, 256, 0, stream>>>(x, ei, ea, aggr);
  add_k<<<ew_blocks, 256, 0, stream>>>(x, aggr, aggr, nelem);
  gemm_k<1><<<dim3(D / 64, N_NODES / 64), 256, 0, stream>>>(
      aggr, D, gin_w1, D, gin_b1, t1, D, nullptr, 0, N_NODES, D, D);
  gemm_k<0><<<dim3(D / 64, N_NODES / 64), 256, 0, stream>>>(
      t1, D, gin_w2, D, gin_b2, hlocal, D, nullptr, 0, N_NODES, D, D);
  bn_stats_k<<<D, 256, 0, stream>>>(x, hlocal, mu, rsig);
  bn_norm_k<<<ew_blocks, 256, 0, stream>>>(x, hlocal, mu, rsig, bn1l_g, bn1l_b, hlocal);

  // ---- gate ----
  gemm_k<1><<<dim3(256 / 64, N_NODES / 64), 256, 0, stream>>>(
      x, D, gate_w1, 256, gate_b1, g1, 256, nullptr, 0, N_NODES, 256, D);
  gate2_k<<<N_NODES / 4, 256, 0, stream>>>(g1, gate_w2, gate_b2, gate);

  // ---- experts (sequential, shared buffers) ----
  for (int e = 0; e < NEXP; ++e) {
    gemm_k<0><<<dim3(2 * D / 64, N_NODES / 64), 256, 0, stream>>>(
        x, D, in_w + (size_t)e * D * 2 * D, 2 * D, nullptr, xz, 2 * D, nullptr, 0,
        N_NODES, 2 * D, D);
    conv_silu_k<<<ew_blocks, 256, 0, stream>>>(xz, conv_w + (size_t)e * D * DCONV,
                                               conv_b + (size_t)e * D, xs);
    gemm_k<0><<<dim3(1, N_NODES / 64), 256, 0, stream>>>(
        xs, D, x_w + (size_t)e * D * 64, 64, nullptr, dbc, 64, nullptr, 0,
        N_NODES, 64, D);
    gemm_k<3><<<dim3(D / 64, N_NODES / 64), 256, 0, stream>>>(
        dbc, 64, dt_w + (size_t)e * DTRANK * D, D, dt_b + (size_t)e * D, dtb, D,
        nullptr, 0, N_NODES, D, DTRANK);
    const float* Al = A_log + (size_t)e * D * DSTATE;
    scanA_k<<<NCHUNK, D, 0, stream>>>(dtb, xs, dbc, Al, Qb, dtsum);
    scanB_k<<<(D * DSTATE) / 256, 256, 0, stream>>>(Qb, dtsum, Al, Hin);
    scanC_k<<<NCHUNK, D, 0, stream>>>(dtb, xs, dbc, Al, Hin, xz, Dp + (size_t)e * D, ubuf);
    gemm_k<2><<<dim3(D / 64, N_NODES / 64), 256, 0, stream>>>(
        ubuf, D, out_w + (size_t)e * D * D, D, nullptr, hattn, D, gate + e, NEXP,
        N_NODES, D, D);
  }

  // ---- attn BN, combine, FFN, final BN ----
  bn_stats_k<<<D, 256, 0, stream>>>(x, hattn, mu, rsig);
  bn_norm_k<<<ew_blocks, 256, 0, stream>>>(x, hattn, mu, rsig, bn1a_g, bn1a_b, hattn);
  add_k<<<ew_blocks, 256, 0, stream>>>(hlocal, hattn, t1, nelem);
  gemm_k<1><<<dim3(2 * D / 64, N_NODES / 64), 256, 0, stream>>>(
      t1, D, ff_w1, 2 * D, ff_b1, xz, 2 * D, nullptr, 0, N_NODES, 2 * D, D);
  gemm_k<0><<<dim3(D / 64, N_NODES / 64), 256, 0, stream>>>(
      xz, 2 * D, ff_w2, D, ff_b2, xs, D, nullptr, 0, N_NODES, D, 2 * D);
  bn_stats_k<<<D, 256, 0, stream>>>(t1, xs, mu, rsig);
  bn_norm_k<<<ew_blocks, 256, 0, stream>>>(t1, xs, mu, rsig, bn2_g, bn2_b, out);
}

// Round 3
// 644.096 us; speedup vs baseline: 3.2973x; 2.5252x over previous
//
#include <hip/hip_runtime.h>
#include <hip/hip_bf16.h>
#include <math.h>

#define N_NODES 4096
#define E_EDGE 65536
#define D 512
#define NEXP 4
#define DSTATE 16
#define DCONV 4
#define DTRANK 32
#define EPS 1e-5f
#define LCHUNK 32
#define NCHUNK (N_NODES / LCHUNK)

typedef __hip_bfloat16 bf16;
typedef short bf16x8 __attribute__((ext_vector_type(8)));
typedef float f32x4 __attribute__((ext_vector_type(4)));

__device__ __forceinline__ float siluf(float x) { return x / (1.f + __expf(-x)); }
__device__ __forceinline__ float softplusf(float x) {
  return (x > 20.f) ? x : log1pf(__expf(x));
}

// async global->LDS, 16B per lane; lds dest must be wave-uniform base (HW adds lane*16)
__device__ __forceinline__ void gload16(const void* g, void* l) {
  __builtin_amdgcn_global_load_lds(
      (const __attribute__((address_space(1))) void*)g,
      (__attribute__((address_space(3))) void*)l, 16, 0, 0);
}

// ---------------- MFMA bf16 GEMM ------------------------------------------
// C(MxN) = A(MxK) @ Bt(NxK)^T. A,Bt bf16 row-major (lda/ldb elems, both %8==0).
// BM=128, BN=FN*32, 256 thr = 4 waves (2x2), wave tile 64 x FN*16, BK=32.
// EPI 0: C=A@B(+bias); EPI 1: relu(+bias); EPI 2: Cf[..] atomicAdd gate-scaled.
// M=4096 fixed via grid.y=32. grid.z batches (strides sA/sB/sC elems).
template <int FN, int EPI>
__global__ __launch_bounds__(256, 2) void mm_k(
    const bf16* __restrict__ A, int lda, long sA,
    const bf16* __restrict__ Bt, int ldb, long sB,
    const float* __restrict__ bias,
    float* __restrict__ Cf, bf16* __restrict__ Cb, int ldc, long sC,
    const float* __restrict__ gate, int ge, int K) {
  constexpr int BN = FN * 32;
  __shared__ __align__(16) bf16 As[128 * 32];
  __shared__ __align__(16) bf16 Bs[BN * 32];
  const int z = blockIdx.z;
  A += (size_t)z * sA;
  Bt += (size_t)z * sB;
  const int tid = threadIdx.x;
  const int w = tid >> 6, l = tid & 63;
  const int wr = w >> 1, wc = w & 1;
  const int bm = blockIdx.y * 128, bn = blockIdx.x * BN;

  f32x4 acc[4][FN];
#pragma unroll
  for (int i = 0; i < 4; ++i)
#pragma unroll
    for (int j = 0; j < FN; ++j) acc[i][j] = 0.f;

  // staging: each wave stages 16 rows (64B each) per call; lane l -> row l>>2, chunk l&3
  const int srow = l >> 2, schunk = l & 3;
  const bf16* gA = A + (size_t)(bm + w * 16 + srow) * lda + schunk * 8;
  const bf16* gB = Bt + (size_t)(bn + w * 16 + srow) * ldb + schunk * 8;
  bf16* lA = As + w * 512;
  bf16* lB = Bs + w * 512;

  const int ar = wr * 64 + (l & 15);
  const int br = wc * FN * 16 + (l & 15);
  const int kb = l >> 4;

  for (int k0 = 0; k0 < K; k0 += 32) {
    gload16(gA + k0, lA);
    gload16(gA + k0 + (size_t)64 * lda, lA + 64 * 32);
    gload16(gB + k0, lB);
    if (FN == 4) gload16(gB + k0 + (size_t)64 * ldb, lB + 64 * 32);
    __syncthreads();
    const bf16x8* Ap = (const bf16x8*)As;
    const bf16x8* Bp = (const bf16x8*)Bs;
    bf16x8 af[4], bfr[FN];
#pragma unroll
    for (int i = 0; i < 4; ++i) af[i] = Ap[(ar + i * 16) * 4 + kb];
#pragma unroll
    for (int j = 0; j < FN; ++j) bfr[j] = Bp[(br + j * 16) * 4 + kb];
#pragma unroll
    for (int i = 0; i < 4; ++i)
#pragma unroll
      for (int j = 0; j < FN; ++j)
        acc[i][j] = __builtin_amdgcn_mfma_f32_16x16x32_bf16(af[i], bfr[j], acc[i][j], 0, 0, 0);
    __syncthreads();
  }

  if (Cf) Cf += (size_t)z * sC;
  if (Cb) Cb += (size_t)z * sC;
  const int r0 = bm + wr * 64 + (l >> 4) * 4;
  const int c0 = bn + wc * FN * 16 + (l & 15);
#pragma unroll
  for (int i = 0; i < 4; ++i)
#pragma unroll
    for (int j = 0; j < FN; ++j) {
      const int col = c0 + j * 16;
      const float bv = bias ? bias[col] : 0.f;
#pragma unroll
      for (int r = 0; r < 4; ++r) {
        const int row = r0 + i * 16 + r;
        float v = acc[i][j][r] + bv;
        if (EPI == 1) v = fmaxf(v, 0.f);
        if (EPI == 2) {
          atomicAdd(&Cf[(size_t)row * ldc + col], gate[row * NEXP + ge + z] * v);
        } else {
          if (Cf) Cf[(size_t)row * ldc + col] = v;
          if (Cb) Cb[(size_t)row * ldc + col] = __float2bfloat16(v);
        }
      }
    }
}

// ---------------- weight transpose+convert: in[K][N] f32 -> out[N][K] bf16 --
__global__ __launch_bounds__(256) void wtrans_k(const float* __restrict__ in,
                                                bf16* __restrict__ out, int K, int N) {
  __shared__ float t[32][33];
  const size_t zo = (size_t)blockIdx.z * K * N;
  in += zo;
  out += zo;
  const int n0 = blockIdx.x * 32, k0 = blockIdx.y * 32;
  const int tx = threadIdx.x & 31, ty = threadIdx.x >> 5;
  for (int i = ty; i < 32; i += 8) t[i][tx] = in[(size_t)(k0 + i) * N + n0 + tx];
  __syncthreads();
  for (int i = ty; i < 32; i += 8)
    out[(size_t)(n0 + i) * K + k0 + tx] = __float2bfloat16(t[tx][i]);
}

// ---------------- small elementwise kernels --------------------------------
__global__ void cvt_k(const float* __restrict__ a, bf16* __restrict__ o, int n) {
  int i = blockIdx.x * blockDim.x + threadIdx.x;
  if (i < n) o[i] = __float2bfloat16(a[i]);
}
__global__ void addcvt_k(const float* __restrict__ a, const float* __restrict__ b,
                         bf16* __restrict__ o, int n) {
  int i = blockIdx.x * blockDim.x + threadIdx.x;
  if (i < n) o[i] = __float2bfloat16(a[i] + b[i]);
}
__global__ void addcvt2_k(const float* __restrict__ a, const float* __restrict__ b,
                          float* __restrict__ of, bf16* __restrict__ ob, int n) {
  int i = blockIdx.x * blockDim.x + threadIdx.x;
  if (i < n) {
    float v = a[i] + b[i];
    of[i] = v;
    ob[i] = __float2bfloat16(v);
  }
}

// ---------------- edge aggregation ----------------------------------------
__global__ void edge_aggr_k(const float* __restrict__ x, const int* __restrict__ ei,
                            const float* __restrict__ ea, float* __restrict__ aggr) {
  int e = blockIdx.x;
  int src = ei[e];
  int dst = ei[E_EDGE + e];
  for (int d = threadIdx.x; d < D; d += blockDim.x) {
    float v = x[(size_t)src * D + d] + ea[(size_t)e * D + d];
    v = fmaxf(v, 0.f);
    atomicAdd(&aggr[(size_t)dst * D + d], v);
  }
}

// ---------------- gate second layer + softmax ------------------------------
__global__ __launch_bounds__(256) void gate2_k(const float* __restrict__ g1,
                                               const float* __restrict__ w2,
                                               const float* __restrict__ b2,
                                               float* __restrict__ gate) {
  int row = blockIdx.x * 4 + (threadIdx.x >> 6);
  int lane = threadIdx.x & 63;
  float a0 = 0.f, a1 = 0.f, a2 = 0.f, a3 = 0.f;
  for (int k = lane; k < 256; k += 64) {
    float v = g1[(size_t)row * 256 + k];
    a0 = fmaf(v, w2[k * 4 + 0], a0);
    a1 = fmaf(v, w2[k * 4 + 1], a1);
    a2 = fmaf(v, w2[k * 4 + 2], a2);
    a3 = fmaf(v, w2[k * 4 + 3], a3);
  }
#pragma unroll
  for (int off = 32; off; off >>= 1) {
    a0 += __shfl_down(a0, off);
    a1 += __shfl_down(a1, off);
    a2 += __shfl_down(a2, off);
    a3 += __shfl_down(a3, off);
  }
  if (lane == 0) {
    float l0 = a0 + b2[0], l1 = a1 + b2[1], l2 = a2 + b2[2], l3 = a3 + b2[3];
    float m = fmaxf(fmaxf(l0, l1), fmaxf(l2, l3));
    float e0 = __expf(l0 - m), e1 = __expf(l1 - m), e2 = __expf(l2 - m), e3 = __expf(l3 - m);
    float s = 1.f / (e0 + e1 + e2 + e3);
    gate[row * 4 + 0] = e0 * s;
    gate[row * 4 + 1] = e1 * s;
    gate[row * 4 + 2] = e2 * s;
    gate[row * 4 + 3] = e3 * s;
  }
}

// ---------------- causal depthwise conv + silu -> bf16 ---------------------
__global__ void conv_silu_k(const float* __restrict__ xz, const float* __restrict__ cw,
                            const float* __restrict__ cb, bf16* __restrict__ xs, int e0) {
  const int z = blockIdx.y;
  xz += (size_t)z * N_NODES * 2 * D;
  xs += (size_t)z * N_NODES * D;
  cw += (size_t)(e0 + z) * D * DCONV;
  cb += (size_t)(e0 + z) * D;
  int idx = blockIdx.x * blockDim.x + threadIdx.x;
  if (idx >= N_NODES * D) return;
  int t = idx >> 9;
  int d = idx & (D - 1);
  float acc = cb[d];
#pragma unroll
  for (int k = 0; k < DCONV; ++k) {
    int tt = t + k - (DCONV - 1);
    if (tt >= 0) acc = fmaf(cw[d * DCONV + k], xz[(size_t)tt * (2 * D) + d], acc);
  }
  xs[idx] = __float2bfloat16(siluf(acc));
}

// ---------------- fused dt: softplus(dbc[:, :32] @ dt_w + dt_b) ------------
__global__ void dt_k(const float* __restrict__ dbc, const float* __restrict__ dtw,
                     const float* __restrict__ dtbias, float* __restrict__ dt, int e0) {
  const int z = blockIdx.y;
  dbc += (size_t)z * N_NODES * 64;
  dt += (size_t)z * N_NODES * D;
  dtw += (size_t)(e0 + z) * DTRANK * D;
  dtbias += (size_t)(e0 + z) * D;
  int idx = blockIdx.x * blockDim.x + threadIdx.x;
  int t = idx >> 9, d = idx & (D - 1);
  float acc = dtbias[d];
#pragma unroll
  for (int k = 0; k < DTRANK; ++k) acc = fmaf(dbc[t * 64 + k], dtw[k * D + d], acc);
  dt[idx] = softplusf(acc);
}

// ---------------- BN stats / norm ------------------------------------------
__global__ __launch_bounds__(256) void bn_stats_k(const float* __restrict__ p,
                                                  const float* __restrict__ q,
                                                  float* __restrict__ mu,
                                                  float* __restrict__ rsig) {
  int d = blockIdx.x;
  float s = 0.f, s2 = 0.f;
  for (int r = threadIdx.x; r < N_NODES; r += 256) {
    float v = p[(size_t)r * D + d] + q[(size_t)r * D + d];
    s += v;
    s2 = fmaf(v, v, s2);
  }
  __shared__ float sh[256], sh2[256];
  sh[threadIdx.x] = s;
  sh2[threadIdx.x] = s2;
  __syncthreads();
  for (int off = 128; off; off >>= 1) {
    if (threadIdx.x < off) {
      sh[threadIdx.x] += sh[threadIdx.x + off];
      sh2[threadIdx.x] += sh2[threadIdx.x + off];
    }
    __syncthreads();
  }
  if (threadIdx.x == 0) {
    float m = sh[0] / N_NODES;
    float var = sh2[0] / N_NODES - m * m;
    mu[d] = m;
    rsig[d] = rsqrtf(var + EPS);
  }
}

__global__ void bn_norm_k(const float* __restrict__ p, const float* __restrict__ q,
                          const float* __restrict__ mu, const float* __restrict__ rsig,
                          const float* __restrict__ g, const float* __restrict__ b,
                          float* __restrict__ o) {
  int idx = blockIdx.x * blockDim.x + threadIdx.x;
  if (idx >= N_NODES * D) return;
  int d = idx & (D - 1);
  o[idx] = (p[idx] + q[idx] - mu[d]) * rsig[d] * g[d] + b[d];
}

// ---------------- chunked selective scan -----------------------------------
__global__ __launch_bounds__(512) void scanA_k(const float* __restrict__ dt,
                                               const bf16* __restrict__ xs,
                                               const float* __restrict__ dbc,
                                               const float* __restrict__ Alog,
                                               float* __restrict__ Q,
                                               float* __restrict__ dtsum, int e0) {
  const int z = blockIdx.y;
  dt += (size_t)z * N_NODES * D;
  xs += (size_t)z * N_NODES * D;
  dbc += (size_t)z * N_NODES * 64;
  Alog += (size_t)(e0 + z) * D * DSTATE;
  Q += (size_t)z * NCHUNK * D * DSTATE;
  dtsum += (size_t)z * NCHUNK * D;
  int c = blockIdx.x;
  int d = threadIdx.x;
  float As[DSTATE], h[DSTATE];
#pragma unroll
  for (int s = 0; s < DSTATE; ++s) {
    As[s] = -__expf(Alog[d * DSTATE + s]);
    h[s] = 0.f;
  }
  float dts = 0.f;
  int t0 = c * LCHUNK;
  for (int t = t0; t < t0 + LCHUNK; ++t) {
    float dtv = dt[(size_t)t * D + d];
    float xv = __bfloat162float(xs[(size_t)t * D + d]);
    float bx = dtv * xv;
    dts += dtv;
#pragma unroll
    for (int s = 0; s < DSTATE; ++s) {
      float Bv = dbc[(size_t)t * 64 + DTRANK + s];
      h[s] = fmaf(__expf(dtv * As[s]), h[s], bx * Bv);
    }
  }
  size_t base = ((size_t)c * D + d) * DSTATE;
#pragma unroll
  for (int s = 0; s < DSTATE; ++s) Q[base + s] = h[s];
  dtsum[c * D + d] = dts;
}

__global__ __launch_bounds__(256) void scanB_k(const float* __restrict__ Q,
                                               const float* __restrict__ dtsum,
                                               const float* __restrict__ Alog,
                                               float* __restrict__ Hin, int e0) {
  const int z = blockIdx.y;
  Q += (size_t)z * NCHUNK * D * DSTATE;
  dtsum += (size_t)z * NCHUNK * D;
  Alog += (size_t)(e0 + z) * D * DSTATE;
  Hin += (size_t)z * NCHUNK * D * DSTATE;
  int idx = blockIdx.x * blockDim.x + threadIdx.x;  // d*DSTATE + s
  int d = idx >> 4;
  float As = -__expf(Alog[idx]);
  float h = 0.f;
  for (int c = 0; c < NCHUNK; ++c) {
    size_t base = (size_t)c * D * DSTATE + idx;
    Hin[base] = h;
    h = fmaf(__expf(As * dtsum[c * D + d]), h, Q[base]);
  }
}

__global__ __launch_bounds__(512) void scanC_k(const float* __restrict__ dt,
                                               const bf16* __restrict__ xs,
                                               const float* __restrict__ dbc,
                                               const float* __restrict__ Alog,
                                               const float* __restrict__ Hin,
                                               const float* __restrict__ xz,
                                               const float* __restrict__ Dp,
                                               bf16* __restrict__ u, int e0) {
  const int z = blockIdx.y;
  dt += (size_t)z * N_NODES * D;
  xs += (size_t)z * N_NODES * D;
  dbc += (size_t)z * N_NODES * 64;
  Alog += (size_t)(e0 + z) * D * DSTATE;
  Hin += (size_t)z * NCHUNK * D * DSTATE;
  xz += (size_t)z * N_NODES * 2 * D;
  Dp += (size_t)(e0 + z) * D;
  u += (size_t)z * N_NODES * D;
  int c = blockIdx.x;
  int d = threadIdx.x;
  float As[DSTATE], h[DSTATE];
  size_t base = ((size_t)c * D + d) * DSTATE;
#pragma unroll
  for (int s = 0; s < DSTATE; ++s) {
    As[s] = -__expf(Alog[d * DSTATE + s]);
    h[s] = Hin[base + s];
  }
  float Dv = Dp[d];
  int t0 = c * LCHUNK;
  for (int t = t0; t < t0 + LCHUNK; ++t) {
    float dtv = dt[(size_t)t * D + d];
    float xv = __bfloat162float(xs[(size_t)t * D + d]);
    float bx = dtv * xv;
    float y = 0.f;
#pragma unroll
    for (int s = 0; s < DSTATE; ++s) {
      float Bv = dbc[(size_t)t * 64 + DTRANK + s];
      float Cv = dbc[(size_t)t * 64 + DTRANK + DSTATE + s];
      h[s] = fmaf(__expf(dtv * As[s]), h[s], bx * Bv);
      y = fmaf(h[s], Cv, y);
    }
    float zv = xz[(size_t)t * (2 * D) + D + d];
    u[(size_t)t * D + d] = __float2bfloat16((y + Dv * xv) * siluf(zv));
  }
}

extern "C" void kernel_launch(void* const* d_in, const int* in_sizes, int n_in,
                              void* d_out, int out_size, void* d_ws, size_t ws_size,
                              hipStream_t stream) {
  const float* x = (const float*)d_in[0];
  const int* ei = (const int*)d_in[1];
  const float* ea = (const float*)d_in[2];
  const float* gin_w1 = (const float*)d_in[3];
  const float* gin_b1 = (const float*)d_in[4];
  const float* gin_w2 = (const float*)d_in[5];
  const float* gin_b2 = (const float*)d_in[6];
  const float* bn1l_g = (const float*)d_in[7];
  const float* bn1l_b = (const float*)d_in[8];
  const float* bn1a_g = (const float*)d_in[9];
  const float* bn1a_b = (const float*)d_in[10];
  const float* bn2_g = (const float*)d_in[11];
  const float* bn2_b = (const float*)d_in[12];
  const float* gate_w1 = (const float*)d_in[13];
  const float* gate_b1 = (const float*)d_in[14];
  const float* gate_w2 = (const float*)d_in[15];
  const float* gate_b2 = (const float*)d_in[16];
  const float* in_w = (const float*)d_in[17];
  const float* conv_w = (const float*)d_in[18];
  const float* conv_b = (const float*)d_in[19];
  const float* x_w = (const float*)d_in[20];
  const float* dt_w = (const float*)d_in[21];
  const float* dt_b = (const float*)d_in[22];
  const float* A_log = (const float*)d_in[23];
  const float* Dp = (const float*)d_in[24];
  const float* out_w = (const float*)d_in[25];
  const float* ff_w1 = (const float*)d_in[26];
  const float* ff_b1 = (const float*)d_in[27];
  const float* ff_w2 = (const float*)d_in[28];
  const float* ff_b2 = (const float*)d_in[29];
  float* out = (float*)d_out;

  const size_t ND = (size_t)N_NODES * D;  // 2M elems
  const size_t NDb = ND / 2;              // bf16 buffer in float units

  // per-EB float requirement
  const size_t fixed_f = 3 * ND + (size_t)N_NODES * 256 + 16384 + 2490624 + ND + 2048;
  const size_t per_f = 2 * ND + NDb + (size_t)N_NODES * 64 + ND +
                       2 * (size_t)NCHUNK * D * DSTATE + (size_t)NCHUNK * D + NDb;
  const int EB = (ws_size >= (fixed_f + 4 * per_f + 65536) * sizeof(float)) ? 4 : 1;

  float* ws = (float*)d_ws;
  size_t off = 0;
  auto alloc = [&](size_t n) {
    float* p = ws + off;
    off += (n + 63) & ~(size_t)63;
    return p;
  };
  float* aggr = alloc(ND);     // later: ffo
  float* pbuf = alloc(ND);     // hpre_bf + t1_bf; later: ffh_bf
  float* hlocal = alloc(ND);
  float* g1 = alloc((size_t)N_NODES * 256);
  float* gate = alloc((size_t)N_NODES * NEXP);
  bf16* gw1t = (bf16*)alloc(131072);
  bf16* gw2t = (bf16*)alloc(131072);
  bf16* gatew1t = (bf16*)alloc(65536);
  bf16* inwt = (bf16*)alloc(1048576);
  bf16* xwt = (bf16*)alloc(65536);
  bf16* outwt = (bf16*)alloc(524288);
  bf16* ffw1t = (bf16*)alloc(262144);
  bf16* ffw2t = (bf16*)alloc(262144);
  float* xbf_f = alloc(NDb);
  float* xz = alloc((size_t)EB * 2 * ND);  // later: h (fp32) + h_bf
  float* xs_f = alloc((size_t)EB * NDb);
  float* dbc = alloc((size_t)EB * N_NODES * 64);
  float* dtb = alloc((size_t)EB * ND);
  float* Qb = alloc((size_t)EB * NCHUNK * D * DSTATE);
  float* Hin = alloc((size_t)EB * NCHUNK * D * DSTATE);
  float* dtsum = alloc((size_t)EB * NCHUNK * D);
  float* ubuf_f = alloc((size_t)EB * NDb);
  float* hattn = alloc(ND);
  float* mu = alloc(D);
  float* rsig = alloc(D);

  bf16* x_bf = (bf16*)xbf_f;
  bf16* hpre_bf = (bf16*)pbuf;
  bf16* t1_bf = (bf16*)(pbuf + NDb);
  bf16* xs_bf = (bf16*)xs_f;
  bf16* ubuf_bf = (bf16*)ubuf_f;
  // phase-4 aliases (source buffers dead by then)
  float* hcomb = xz;                 // h = hlocal + hattn (fp32)
  bf16* hcomb_bf = (bf16*)(xz + ND);
  bf16* ffh_bf = (bf16*)pbuf;        // ff hidden, 4096x1024 bf16 = 8MB
  float* ffo = aggr;                 // ff out fp32

  const int nelem = N_NODES * D;
  const int ew = (nelem + 255) / 256;

  hipMemsetAsync(aggr, 0, ND * sizeof(float), stream);
  hipMemsetAsync(hattn, 0, ND * sizeof(float), stream);

  // ---- weight transposes (f32 [K][N] -> bf16 [N][K]) ----
  wtrans_k<<<dim3(16, 16, 1), 256, 0, stream>>>(gin_w1, gw1t, 512, 512);
  wtrans_k<<<dim3(16, 16, 1), 256, 0, stream>>>(gin_w2, gw2t, 512, 512);
  wtrans_k<<<dim3(8, 16, 1), 256, 0, stream>>>(gate_w1, gatew1t, 512, 256);
  wtrans_k<<<dim3(32, 16, 4), 256, 0, stream>>>(in_w, inwt, 512, 1024);
  wtrans_k<<<dim3(2, 16, 4), 256, 0, stream>>>(x_w, xwt, 512, 64);
  wtrans_k<<<dim3(16, 16, 4), 256, 0, stream>>>(out_w, outwt, 512, 512);
  wtrans_k<<<dim3(32, 16, 1), 256, 0, stream>>>(ff_w1, ffw1t, 512, 1024);
  wtrans_k<<<dim3(16, 32, 1), 256, 0, stream>>>(ff_w2, ffw2t, 1024, 512);
  cvt_k<<<ew, 256, 0, stream>>>(x, x_bf, nelem);

  // ---- GIN local branch ----
  edge_aggr_k<<<E_EDGE, 256, 0, stream>>>(x, ei, ea, aggr);
  addcvt_k<<<ew, 256, 0, stream>>>(x, aggr, hpre_bf, nelem);
  mm_k<4, 1><<<dim3(4, 32, 1), 256, 0, stream>>>(hpre_bf, 512, 0, gw1t, 512, 0, gin_b1,
                                                 nullptr, t1_bf, 512, 0, nullptr, 0, 512);
  mm_k<4, 0><<<dim3(4, 32, 1), 256, 0, stream>>>(t1_bf, 512, 0, gw2t, 512, 0, gin_b2,
                                                 hlocal, nullptr, 512, 0, nullptr, 0, 512);
  bn_stats_k<<<D, 256, 0, stream>>>(x, hlocal, mu, rsig);
  bn_norm_k<<<ew, 256, 0, stream>>>(x, hlocal, mu, rsig, bn1l_g, bn1l_b, hlocal);

  // ---- gate ----
  mm_k<4, 1><<<dim3(2, 32, 1), 256, 0, stream>>>(x_bf, 512, 0, gatew1t, 512, 0, gate_b1,
                                                 g1, nullptr, 256, 0, nullptr, 0, 512);
  gate2_k<<<N_NODES / 4, 256, 0, stream>>>(g1, gate_w2, gate_b2, gate);

  // ---- experts (z-batched by EB) ----
  for (int e0 = 0; e0 < NEXP; e0 += EB) {
    mm_k<4, 0><<<dim3(8, 32, EB), 256, 0, stream>>>(
        x_bf, 512, 0, inwt + (size_t)e0 * 512 * 1024, 512, (long)512 * 1024, nullptr,
        xz, nullptr, 1024, (long)2 * ND, nullptr, 0, 512);
    conv_silu_k<<<dim3(ew, EB), 256, 0, stream>>>(xz, conv_w, conv_b, xs_bf, e0);
    mm_k<2, 0><<<dim3(1, 32, EB), 256, 0, stream>>>(
        xs_bf, 512, (long)ND, xwt + (size_t)e0 * 64 * 512, 512, (long)64 * 512, nullptr,
        dbc, nullptr, 64, (long)N_NODES * 64, nullptr, 0, 512);
    dt_k<<<dim3(ew, EB), 256, 0, stream>>>(dbc, dt_w, dt_b, dtb, e0);
    scanA_k<<<dim3(NCHUNK, EB), 512, 0, stream>>>(dtb, xs_bf, dbc, A_log, Qb, dtsum, e0);
    scanB_k<<<dim3((D * DSTATE) / 256, EB), 256, 0, stream>>>(Qb, dtsum, A_log, Hin, e0);
    scanC_k<<<dim3(NCHUNK, EB), 512, 0, stream>>>(dtb, xs_bf, dbc, A_log, Hin, xz, Dp,
                                                  ubuf_bf, e0);
    mm_k<4, 2><<<dim3(4, 32, EB), 256, 0, stream>>>(
        ubuf_bf, 512, (long)ND, outwt + (size_t)e0 * 512 * 512, 512, (long)512 * 512,
        nullptr, hattn, nullptr, 512, 0, gate, e0, 512);
  }

  // ---- attn BN, combine, FFN, final BN ----
  bn_stats_k<<<D, 256, 0, stream>>>(x, hattn, mu, rsig);
  bn_norm_k<<<ew, 256, 0, stream>>>(x, hattn, mu, rsig, bn1a_g, bn1a_b, hattn);
  addcvt2_k<<<ew, 256, 0, stream>>>(hlocal, hattn, hcomb, hcomb_bf, nelem);
  mm_k<4, 1><<<dim3(8, 32, 1), 256, 0, stream>>>(hcomb_bf, 512, 0, ffw1t, 512, 0, ff_b1,
                                                 nullptr, ffh_bf, 1024, 0, nullptr, 0, 512);
  mm_k<4, 0><<<dim3(4, 32, 1), 256, 0, stream>>>(ffh_bf, 1024, 0, ffw2t, 1024, 0, ff_b2,
                                                 ffo, nullptr, 512, 0, nullptr, 0, 1024);
  bn_stats_k<<<D, 256, 0, stream>>>(hcomb, ffo, mu, rsig);
  bn_norm_k<<<ew, 256, 0, stream>>>(hcomb, ffo, mu, rsig, bn2_g, bn2_b, out);
}

// Round 5
// 591.708 us; speedup vs baseline: 3.5893x; 1.0885x over previous
//
#include <hip/hip_runtime.h>
#include <hip/hip_bf16.h>
#include <math.h>

#define N_NODES 4096
#define E_EDGE 65536
#define D 512
#define NEXP 4
#define DSTATE 16
#define DCONV 4
#define DTRANK 32
#define EPS 1e-5f
#define LCHUNK 32
#define NCHUNK (N_NODES / LCHUNK)

typedef __hip_bfloat16 bf16;
typedef short bf16x8 __attribute__((ext_vector_type(8)));
typedef float f32x4 __attribute__((ext_vector_type(4)));

__device__ __forceinline__ float siluf(float x) { return x / (1.f + __expf(-x)); }
__device__ __forceinline__ float softplusf(float x) {
  return (x > 20.f) ? x : log1pf(__expf(x));
}

// async global->LDS, 16B per lane; lds dest must be wave-uniform base (HW adds lane*16)
__device__ __forceinline__ void gload16(const void* g, void* l) {
  __builtin_amdgcn_global_load_lds(
      (const __attribute__((address_space(1))) void*)g,
      (__attribute__((address_space(3))) void*)l, 16, 0, 0);
}

// ---------------- MFMA bf16 GEMM ------------------------------------------
// C(MxN) = A(MxK) @ Bt(NxK)^T. A,Bt bf16 row-major (lda/ldb elems, both %8==0).
// BM=128, BN=FN*32, 256 thr = 4 waves (2x2), wave tile 64 x FN*16, BK=32.
// EPI 0: C=A@B(+bias); EPI 1: relu(+bias); EPI 2: Cf[..] atomicAdd gate-scaled.
template <int FN, int EPI>
__global__ __launch_bounds__(256, 2) void mm_k(
    const bf16* __restrict__ A, int lda, long sA,
    const bf16* __restrict__ Bt, int ldb, long sB,
    const float* __restrict__ bias,
    float* __restrict__ Cf, bf16* __restrict__ Cb, int ldc, long sC,
    const float* __restrict__ gate, int ge, int K) {
  constexpr int BN = FN * 32;
  __shared__ __align__(16) bf16 As[128 * 32];
  __shared__ __align__(16) bf16 Bs[BN * 32];
  const int z = blockIdx.z;
  A += (size_t)z * sA;
  Bt += (size_t)z * sB;
  const int tid = threadIdx.x;
  const int w = tid >> 6, l = tid & 63;
  const int wr = w >> 1, wc = w & 1;
  const int bm = blockIdx.y * 128, bn = blockIdx.x * BN;

  f32x4 acc[4][FN];
#pragma unroll
  for (int i = 0; i < 4; ++i)
#pragma unroll
    for (int j = 0; j < FN; ++j) acc[i][j] = 0.f;

  const int srow = l >> 2, schunk = l & 3;
  const bf16* gA = A + (size_t)(bm + w * 16 + srow) * lda + schunk * 8;
  const bf16* gB = Bt + (size_t)(bn + w * 16 + srow) * ldb + schunk * 8;
  bf16* lA = As + w * 512;
  bf16* lB = Bs + w * 512;

  const int ar = wr * 64 + (l & 15);
  const int br = wc * FN * 16 + (l & 15);
  const int kb = l >> 4;

  for (int k0 = 0; k0 < K; k0 += 32) {
    gload16(gA + k0, lA);
    gload16(gA + k0 + (size_t)64 * lda, lA + 64 * 32);
    gload16(gB + k0, lB);
    if (FN == 4) gload16(gB + k0 + (size_t)64 * ldb, lB + 64 * 32);
    __syncthreads();
    const bf16x8* Ap = (const bf16x8*)As;
    const bf16x8* Bp = (const bf16x8*)Bs;
    bf16x8 af[4], bfr[FN];
#pragma unroll
    for (int i = 0; i < 4; ++i) af[i] = Ap[(ar + i * 16) * 4 + kb];
#pragma unroll
    for (int j = 0; j < FN; ++j) bfr[j] = Bp[(br + j * 16) * 4 + kb];
#pragma unroll
    for (int i = 0; i < 4; ++i)
#pragma unroll
      for (int j = 0; j < FN; ++j)
        acc[i][j] = __builtin_amdgcn_mfma_f32_16x16x32_bf16(af[i], bfr[j], acc[i][j], 0, 0, 0);
    __syncthreads();
  }

  if (Cf) Cf += (size_t)z * sC;
  if (Cb) Cb += (size_t)z * sC;
  const int r0 = bm + wr * 64 + (l >> 4) * 4;
  const int c0 = bn + wc * FN * 16 + (l & 15);
#pragma unroll
  for (int i = 0; i < 4; ++i)
#pragma unroll
    for (int j = 0; j < FN; ++j) {
      const int col = c0 + j * 16;
      const float bv = bias ? bias[col] : 0.f;
#pragma unroll
      for (int r = 0; r < 4; ++r) {
        const int row = r0 + i * 16 + r;
        float v = acc[i][j][r] + bv;
        if (EPI == 1) v = fmaxf(v, 0.f);
        if (EPI == 2) {
          atomicAdd(&Cf[(size_t)row * ldc + col], gate[row * NEXP + ge + z] * v);
        } else {
          if (Cf) Cf[(size_t)row * ldc + col] = v;
          if (Cb) Cb[(size_t)row * ldc + col] = __float2bfloat16(v);
        }
      }
    }
}

// ---------------- weight transpose+convert: in[K][N] f32 -> out[N][K] bf16 --
__global__ __launch_bounds__(256) void wtrans_k(const float* __restrict__ in,
                                                bf16* __restrict__ out, int K, int N) {
  __shared__ float t[32][33];
  const size_t zo = (size_t)blockIdx.z * K * N;
  in += zo;
  out += zo;
  const int n0 = blockIdx.x * 32, k0 = blockIdx.y * 32;
  const int tx = threadIdx.x & 31, ty = threadIdx.x >> 5;
  for (int i = ty; i < 32; i += 8) t[i][tx] = in[(size_t)(k0 + i) * N + n0 + tx];
  __syncthreads();
  for (int i = ty; i < 32; i += 8)
    out[(size_t)(n0 + i) * K + k0 + tx] = __float2bfloat16(t[tx][i]);
}

// ---------------- small elementwise kernels --------------------------------
__global__ void cvt_k(const float* __restrict__ a, bf16* __restrict__ o, int n) {
  int i = blockIdx.x * blockDim.x + threadIdx.x;
  if (i < n) o[i] = __float2bfloat16(a[i]);
}
__global__ void addcvt2_k(const float* __restrict__ a, const float* __restrict__ b,
                          float* __restrict__ of, bf16* __restrict__ ob, int n) {
  int i = blockIdx.x * blockDim.x + threadIdx.x;
  if (i < n) {
    float v = a[i] + b[i];
    of[i] = v;
    ob[i] = __float2bfloat16(v);
  }
}

// ---------------- CSR build: histogram, prefix scan, scatter ---------------
__global__ void hist_k(const int* __restrict__ ei, int* __restrict__ deg) {
  int e = blockIdx.x * 256 + threadIdx.x;
  if (e < E_EDGE) atomicAdd(&deg[ei[E_EDGE + e]], 1);
}

__global__ __launch_bounds__(1024) void prefix_k(const int* __restrict__ deg,
                                                 int* __restrict__ rowstart) {
  __shared__ int s[1024];
  int t = threadIdx.x;
  int base = t * 4;
  int d0 = deg[base], d1 = deg[base + 1], d2 = deg[base + 2], d3 = deg[base + 3];
  int sum = d0 + d1 + d2 + d3;
  s[t] = sum;
  __syncthreads();
  for (int off = 1; off < 1024; off <<= 1) {
    int v = (t >= off) ? s[t - off] : 0;
    __syncthreads();
    s[t] += v;
    __syncthreads();
  }
  int excl = s[t] - sum;
  rowstart[base] = excl;
  rowstart[base + 1] = excl + d0;
  rowstart[base + 2] = excl + d0 + d1;
  rowstart[base + 3] = excl + d0 + d1 + d2;
}

__global__ void scatter_k(const int* __restrict__ ei, const int* __restrict__ rowstart,
                          int* __restrict__ cnt, int* __restrict__ eid) {
  int e = blockIdx.x * 256 + threadIdx.x;
  if (e < E_EDGE) {
    int dst = ei[E_EDGE + e];
    int slot = rowstart[dst] + atomicAdd(&cnt[dst], 1);
    eid[slot] = e;
  }
}

// gather: per-node sum of relu(x[src]+ea[e]); writes hpre_bf = bf16(x[n]+aggr)
__global__ __launch_bounds__(256) void aggr_gather_k(
    const float* __restrict__ x, const int* __restrict__ ei, const float* __restrict__ ea,
    const int* __restrict__ rowstart, const int* __restrict__ deg,
    const int* __restrict__ eid, bf16* __restrict__ hpre) {
  int n = blockIdx.x;
  int tid = threadIdx.x;
  int beg = rowstart[n];
  int end = beg + deg[n];
  float a0 = 0.f, a1 = 0.f;
  int i = beg;
  for (; i + 1 < end; i += 2) {
    int e0 = eid[i], e1 = eid[i + 1];
    int s0 = ei[e0], s1 = ei[e1];
    const float* x0 = x + (size_t)s0 * D;
    const float* e0p = ea + (size_t)e0 * D;
    const float* x1 = x + (size_t)s1 * D;
    const float* e1p = ea + (size_t)e1 * D;
    a0 += fmaxf(x0[tid] + e0p[tid], 0.f) + fmaxf(x1[tid] + e1p[tid], 0.f);
    a1 += fmaxf(x0[tid + 256] + e0p[tid + 256], 0.f) +
          fmaxf(x1[tid + 256] + e1p[tid + 256], 0.f);
  }
  if (i < end) {
    int e0 = eid[i];
    int s0 = ei[e0];
    const float* x0 = x + (size_t)s0 * D;
    const float* e0p = ea + (size_t)e0 * D;
    a0 += fmaxf(x0[tid] + e0p[tid], 0.f);
    a1 += fmaxf(x0[tid + 256] + e0p[tid + 256], 0.f);
  }
  const float* xn = x + (size_t)n * D;
  hpre[(size_t)n * D + tid] = __float2bfloat16(xn[tid] + a0);
  hpre[(size_t)n * D + tid + 256] = __float2bfloat16(xn[tid + 256] + a1);
}

// ---------------- gate second layer + softmax ------------------------------
__global__ __launch_bounds__(256) void gate2_k(const float* __restrict__ g1,
                                               const float* __restrict__ w2,
                                               const float* __restrict__ b2,
                                               float* __restrict__ gate) {
  int row = blockIdx.x * 4 + (threadIdx.x >> 6);
  int lane = threadIdx.x & 63;
  float a0 = 0.f, a1 = 0.f, a2 = 0.f, a3 = 0.f;
  for (int k = lane; k < 256; k += 64) {
    float v = g1[(size_t)row * 256 + k];
    a0 = fmaf(v, w2[k * 4 + 0], a0);
    a1 = fmaf(v, w2[k * 4 + 1], a1);
    a2 = fmaf(v, w2[k * 4 + 2], a2);
    a3 = fmaf(v, w2[k * 4 + 3], a3);
  }
#pragma unroll
  for (int off = 32; off; off >>= 1) {
    a0 += __shfl_down(a0, off);
    a1 += __shfl_down(a1, off);
    a2 += __shfl_down(a2, off);
    a3 += __shfl_down(a3, off);
  }
  if (lane == 0) {
    float l0 = a0 + b2[0], l1 = a1 + b2[1], l2 = a2 + b2[2], l3 = a3 + b2[3];
    float m = fmaxf(fmaxf(l0, l1), fmaxf(l2, l3));
    float e0 = __expf(l0 - m), e1 = __expf(l1 - m), e2 = __expf(l2 - m), e3 = __expf(l3 - m);
    float s = 1.f / (e0 + e1 + e2 + e3);
    gate[row * 4 + 0] = e0 * s;
    gate[row * 4 + 1] = e1 * s;
    gate[row * 4 + 2] = e2 * s;
    gate[row * 4 + 3] = e3 * s;
  }
}

// ---------------- causal depthwise conv + silu -> bf16 ---------------------
__global__ void conv_silu_k(const float* __restrict__ xz, const float* __restrict__ cw,
                            const float* __restrict__ cb, bf16* __restrict__ xs, int e0) {
  const int z = blockIdx.y;
  xz += (size_t)z * N_NODES * 2 * D;
  xs += (size_t)z * N_NODES * D;
  cw += (size_t)(e0 + z) * D * DCONV;
  cb += (size_t)(e0 + z) * D;
  int idx = blockIdx.x * blockDim.x + threadIdx.x;
  if (idx >= N_NODES * D) return;
  int t = idx >> 9;
  int d = idx & (D - 1);
  float acc = cb[d];
#pragma unroll
  for (int k = 0; k < DCONV; ++k) {
    int tt = t + k - (DCONV - 1);
    if (tt >= 0) acc = fmaf(cw[d * DCONV + k], xz[(size_t)tt * (2 * D) + d], acc);
  }
  xs[idx] = __float2bfloat16(siluf(acc));
}

// ---------------- fused dt: softplus(dbc[:, :32] @ dt_w + dt_b) ------------
__global__ void dt_k(const float* __restrict__ dbc, const float* __restrict__ dtw,
                     const float* __restrict__ dtbias, float* __restrict__ dt, int e0) {
  const int z = blockIdx.y;
  dbc += (size_t)z * N_NODES * 64;
  dt += (size_t)z * N_NODES * D;
  dtw += (size_t)(e0 + z) * DTRANK * D;
  dtbias += (size_t)(e0 + z) * D;
  int idx = blockIdx.x * blockDim.x + threadIdx.x;
  int t = idx >> 9, d = idx & (D - 1);
  float acc = dtbias[d];
#pragma unroll
  for (int k = 0; k < DTRANK; ++k) acc = fmaf(dbc[t * 64 + k], dtw[k * D + d], acc);
  dt[idx] = softplusf(acc);
}

// ---------------- BN stats / norm ------------------------------------------
__global__ __launch_bounds__(256) void bn_stats_k(const float* __restrict__ p,
                                                  const float* __restrict__ q,
                                                  float* __restrict__ mu,
                                                  float* __restrict__ rsig) {
  int d = blockIdx.x;
  float s = 0.f, s2 = 0.f;
  for (int r = threadIdx.x; r < N_NODES; r += 256) {
    float v = p[(size_t)r * D + d] + q[(size_t)r * D + d];
    s += v;
    s2 = fmaf(v, v, s2);
  }
  __shared__ float sh[256], sh2[256];
  sh[threadIdx.x] = s;
  sh2[threadIdx.x] = s2;
  __syncthreads();
  for (int off = 128; off; off >>= 1) {
    if (threadIdx.x < off) {
      sh[threadIdx.x] += sh[threadIdx.x + off];
      sh2[threadIdx.x] += sh2[threadIdx.x + off];
    }
    __syncthreads();
  }
  if (threadIdx.x == 0) {
    float m = sh[0] / N_NODES;
    float var = sh2[0] / N_NODES - m * m;
    mu[d] = m;
    rsig[d] = rsqrtf(var + EPS);
  }
}

__global__ void bn_norm_k(const float* __restrict__ p, const float* __restrict__ q,
                          const float* __restrict__ mu, const float* __restrict__ rsig,
                          const float* __restrict__ g, const float* __restrict__ b,
                          float* __restrict__ o) {
  int idx = blockIdx.x * blockDim.x + threadIdx.x;
  if (idx >= N_NODES * D) return;
  int d = idx & (D - 1);
  o[idx] = (p[idx] + q[idx] - mu[d]) * rsig[d] * g[d] + b[d];
}

// ---------------- chunked selective scan -----------------------------------
__global__ __launch_bounds__(512) void scanA_k(const float* __restrict__ dt,
                                               const bf16* __restrict__ xs,
                                               const float* __restrict__ dbc,
                                               const float* __restrict__ Alog,
                                               float* __restrict__ Q,
                                               float* __restrict__ dtsum, int e0) {
  const int z = blockIdx.y;
  dt += (size_t)z * N_NODES * D;
  xs += (size_t)z * N_NODES * D;
  dbc += (size_t)z * N_NODES * 64;
  Alog += (size_t)(e0 + z) * D * DSTATE;
  Q += (size_t)z * NCHUNK * D * DSTATE;
  dtsum += (size_t)z * NCHUNK * D;
  int c = blockIdx.x;
  int d = threadIdx.x;
  float As[DSTATE], h[DSTATE];
#pragma unroll
  for (int s = 0; s < DSTATE; ++s) {
    As[s] = -__expf(Alog[d * DSTATE + s]);
    h[s] = 0.f;
  }
  float dts = 0.f;
  int t0 = c * LCHUNK;
  for (int t = t0; t < t0 + LCHUNK; ++t) {
    float dtv = dt[(size_t)t * D + d];
    float xv = __bfloat162float(xs[(size_t)t * D + d]);
    float bx = dtv * xv;
    dts += dtv;
#pragma unroll
    for (int s = 0; s < DSTATE; ++s) {
      float Bv = dbc[(size_t)t * 64 + DTRANK + s];
      h[s] = fmaf(__expf(dtv * As[s]), h[s], bx * Bv);
    }
  }
  size_t base = ((size_t)c * D + d) * DSTATE;
#pragma unroll
  for (int s = 0; s < DSTATE; ++s) Q[base + s] = h[s];
  dtsum[c * D + d] = dts;
}

__global__ __launch_bounds__(256) void scanB_k(const float* __restrict__ Q,
                                               const float* __restrict__ dtsum,
                                               const float* __restrict__ Alog,
                                               float* __restrict__ Hin, int e0) {
  const int z = blockIdx.y;
  Q += (size_t)z * NCHUNK * D * DSTATE;
  dtsum += (size_t)z * NCHUNK * D;
  Alog += (size_t)(e0 + z) * D * DSTATE;
  Hin += (size_t)z * NCHUNK * D * DSTATE;
  int idx = blockIdx.x * blockDim.x + threadIdx.x;  // d*DSTATE + s
  int d = idx >> 4;
  float As = -__expf(Alog[idx]);
  float h = 0.f;
  for (int c = 0; c < NCHUNK; ++c) {
    size_t base = (size_t)c * D * DSTATE + idx;
    Hin[base] = h;
    h = fmaf(__expf(As * dtsum[c * D + d]), h, Q[base]);
  }
}

__global__ __launch_bounds__(512) void scanC_k(const float* __restrict__ dt,
                                               const bf16* __restrict__ xs,
                                               const float* __restrict__ dbc,
                                               const float* __restrict__ Alog,
                                               const float* __restrict__ Hin,
                                               const float* __restrict__ xz,
                                               const float* __restrict__ Dp,
                                               bf16* __restrict__ u, int e0) {
  const int z = blockIdx.y;
  dt += (size_t)z * N_NODES * D;
  xs += (size_t)z * N_NODES * D;
  dbc += (size_t)z * N_NODES * 64;
  Alog += (size_t)(e0 + z) * D * DSTATE;
  Hin += (size_t)z * NCHUNK * D * DSTATE;
  xz += (size_t)z * N_NODES * 2 * D;
  Dp += (size_t)(e0 + z) * D;
  u += (size_t)z * N_NODES * D;
  int c = blockIdx.x;
  int d = threadIdx.x;
  float As[DSTATE], h[DSTATE];
  size_t base = ((size_t)c * D + d) * DSTATE;
#pragma unroll
  for (int s = 0; s < DSTATE; ++s) {
    As[s] = -__expf(Alog[d * DSTATE + s]);
    h[s] = Hin[base + s];
  }
  float Dv = Dp[d];
  int t0 = c * LCHUNK;
  for (int t = t0; t < t0 + LCHUNK; ++t) {
    float dtv = dt[(size_t)t * D + d];
    float xv = __bfloat162float(xs[(size_t)t * D + d]);
    float bx = dtv * xv;
    float y = 0.f;
#pragma unroll
    for (int s = 0; s < DSTATE; ++s) {
      float Bv = dbc[(size_t)t * 64 + DTRANK + s];
      float Cv = dbc[(size_t)t * 64 + DTRANK + DSTATE + s];
      h[s] = fmaf(__expf(dtv * As[s]), h[s], bx * Bv);
      y = fmaf(h[s], Cv, y);
    }
    float zv = xz[(size_t)t * (2 * D) + D + d];
    u[(size_t)t * D + d] = __float2bfloat16((y + Dv * xv) * siluf(zv));
  }
}

extern "C" void kernel_launch(void* const* d_in, const int* in_sizes, int n_in,
                              void* d_out, int out_size, void* d_ws, size_t ws_size,
                              hipStream_t stream) {
  const float* x = (const float*)d_in[0];
  const int* ei = (const int*)d_in[1];
  const float* ea = (const float*)d_in[2];
  const float* gin_w1 = (const float*)d_in[3];
  const float* gin_b1 = (const float*)d_in[4];
  const float* gin_w2 = (const float*)d_in[5];
  const float* gin_b2 = (const float*)d_in[6];
  const float* bn1l_g = (const float*)d_in[7];
  const float* bn1l_b = (const float*)d_in[8];
  const float* bn1a_g = (const float*)d_in[9];
  const float* bn1a_b = (const float*)d_in[10];
  const float* bn2_g = (const float*)d_in[11];
  const float* bn2_b = (const float*)d_in[12];
  const float* gate_w1 = (const float*)d_in[13];
  const float* gate_b1 = (const float*)d_in[14];
  const float* gate_w2 = (const float*)d_in[15];
  const float* gate_b2 = (const float*)d_in[16];
  const float* in_w = (const float*)d_in[17];
  const float* conv_w = (const float*)d_in[18];
  const float* conv_b = (const float*)d_in[19];
  const float* x_w = (const float*)d_in[20];
  const float* dt_w = (const float*)d_in[21];
  const float* dt_b = (const float*)d_in[22];
  const float* A_log = (const float*)d_in[23];
  const float* Dp = (const float*)d_in[24];
  const float* out_w = (const float*)d_in[25];
  const float* ff_w1 = (const float*)d_in[26];
  const float* ff_b1 = (const float*)d_in[27];
  const float* ff_w2 = (const float*)d_in[28];
  const float* ff_b2 = (const float*)d_in[29];
  float* out = (float*)d_out;

  const size_t ND = (size_t)N_NODES * D;  // 2M elems
  const size_t NDb = ND / 2;              // bf16 buffer in float units

  const size_t fixed_f = 3 * ND + (size_t)N_NODES * 256 + 16384 + 2490624 + ND + 2048 + 81920;
  const size_t per_f = 2 * ND + NDb + (size_t)N_NODES * 64 + ND +
                       2 * (size_t)NCHUNK * D * DSTATE + (size_t)NCHUNK * D + NDb;
  const int EB = (ws_size >= (fixed_f + 4 * per_f + 65536) * sizeof(float)) ? 4 : 1;

  float* ws = (float*)d_ws;
  size_t off = 0;
  auto alloc = [&](size_t n) {
    float* p = ws + off;
    off += (n + 63) & ~(size_t)63;
    return p;
  };
  float* aggr = alloc(ND);     // only used as ffo in phase 4 now
  float* pbuf = alloc(ND);     // hpre_bf + t1_bf; later: ffh_bf
  float* hlocal = alloc(ND);
  float* g1 = alloc((size_t)N_NODES * 256);
  float* gate = alloc((size_t)N_NODES * NEXP);
  bf16* gw1t = (bf16*)alloc(131072);
  bf16* gw2t = (bf16*)alloc(131072);
  bf16* gatew1t = (bf16*)alloc(65536);
  bf16* inwt = (bf16*)alloc(1048576);
  bf16* xwt = (bf16*)alloc(65536);
  bf16* outwt = (bf16*)alloc(524288);
  bf16* ffw1t = (bf16*)alloc(262144);
  bf16* ffw2t = (bf16*)alloc(262144);
  // CSR buffers (1 int == 1 float == 4B, alloc() counts elements)
  int* deg = (int*)alloc(N_NODES);       // 4096 ints
  int* eid = (int*)alloc(E_EDGE);        // 65536 ints
  int* cnt = (int*)alloc(N_NODES);       // 4096 ints
  int* rowstart = (int*)alloc(N_NODES);  // 4096 ints
  float* xbf_f = alloc(NDb);
  float* xz = alloc((size_t)EB * 2 * ND);  // later: h (fp32) + h_bf
  float* xs_f = alloc((size_t)EB * NDb);
  float* dbc = alloc((size_t)EB * N_NODES * 64);
  float* dtb = alloc((size_t)EB * ND);
  float* Qb = alloc((size_t)EB * NCHUNK * D * DSTATE);
  float* Hin = alloc((size_t)EB * NCHUNK * D * DSTATE);
  float* dtsum = alloc((size_t)EB * NCHUNK * D);
  float* ubuf_f = alloc((size_t)EB * NDb);
  float* hattn = alloc(ND);
  float* mu = alloc(D);
  float* rsig = alloc(D);

  bf16* x_bf = (bf16*)xbf_f;
  bf16* hpre_bf = (bf16*)pbuf;
  bf16* t1_bf = (bf16*)(pbuf + NDb);
  bf16* xs_bf = (bf16*)xs_f;
  bf16* ubuf_bf = (bf16*)ubuf_f;
  float* hcomb = xz;
  bf16* hcomb_bf = (bf16*)(xz + ND);
  bf16* ffh_bf = (bf16*)pbuf;
  float* ffo = aggr;

  const int nelem = N_NODES * D;
  const int ew = (nelem + 255) / 256;

  hipMemsetAsync(deg, 0, N_NODES * sizeof(int), stream);
  hipMemsetAsync(cnt, 0, N_NODES * sizeof(int), stream);
  hipMemsetAsync(hattn, 0, ND * sizeof(float), stream);

  // ---- weight transposes (f32 [K][N] -> bf16 [N][K]) ----
  wtrans_k<<<dim3(16, 16, 1), 256, 0, stream>>>(gin_w1, gw1t, 512, 512);
  wtrans_k<<<dim3(16, 16, 1), 256, 0, stream>>>(gin_w2, gw2t, 512, 512);
  wtrans_k<<<dim3(8, 16, 1), 256, 0, stream>>>(gate_w1, gatew1t, 512, 256);
  wtrans_k<<<dim3(32, 16, 4), 256, 0, stream>>>(in_w, inwt, 512, 1024);
  wtrans_k<<<dim3(2, 16, 4), 256, 0, stream>>>(x_w, xwt, 512, 64);
  wtrans_k<<<dim3(16, 16, 4), 256, 0, stream>>>(out_w, outwt, 512, 512);
  wtrans_k<<<dim3(32, 16, 1), 256, 0, stream>>>(ff_w1, ffw1t, 512, 1024);
  wtrans_k<<<dim3(16, 32, 1), 256, 0, stream>>>(ff_w2, ffw2t, 1024, 512);
  cvt_k<<<ew, 256, 0, stream>>>(x, x_bf, nelem);

  // ---- CSR build + GIN local branch ----
  hist_k<<<E_EDGE / 256, 256, 0, stream>>>(ei, deg);
  prefix_k<<<1, 1024, 0, stream>>>(deg, rowstart);
  scatter_k<<<E_EDGE / 256, 256, 0, stream>>>(ei, rowstart, cnt, eid);
  aggr_gather_k<<<N_NODES, 256, 0, stream>>>(x, ei, ea, rowstart, deg, eid, hpre_bf);
  mm_k<4, 1><<<dim3(4, 32, 1), 256, 0, stream>>>(hpre_bf, 512, 0, gw1t, 512, 0, gin_b1,
                                                 nullptr, t1_bf, 512, 0, nullptr, 0, 512);
  mm_k<4, 0><<<dim3(4, 32, 1), 256, 0, stream>>>(t1_bf, 512, 0, gw2t, 512, 0, gin_b2,
                                                 hlocal, nullptr, 512, 0, nullptr, 0, 512);
  bn_stats_k<<<D, 256, 0, stream>>>(x, hlocal, mu, rsig);
  bn_norm_k<<<ew, 256, 0, stream>>>(x, hlocal, mu, rsig, bn1l_g, bn1l_b, hlocal);

  // ---- gate ----
  mm_k<4, 1><<<dim3(2, 32, 1), 256, 0, stream>>>(x_bf, 512, 0, gatew1t, 512, 0, gate_b1,
                                                 g1, nullptr, 256, 0, nullptr, 0, 512);
  gate2_k<<<N_NODES / 4, 256, 0, stream>>>(g1, gate_w2, gate_b2, gate);

  // ---- experts (z-batched by EB) ----
  for (int e0 = 0; e0 < NEXP; e0 += EB) {
    mm_k<4, 0><<<dim3(8, 32, EB), 256, 0, stream>>>(
        x_bf, 512, 0, inwt + (size_t)e0 * 512 * 1024, 512, (long)512 * 1024, nullptr,
        xz, nullptr, 1024, (long)2 * ND, nullptr, 0, 512);
    conv_silu_k<<<dim3(ew, EB), 256, 0, stream>>>(xz, conv_w, conv_b, xs_bf, e0);
    mm_k<2, 0><<<dim3(1, 32, EB), 256, 0, stream>>>(
        xs_bf, 512, (long)ND, xwt + (size_t)e0 * 64 * 512, 512, (long)64 * 512, nullptr,
        dbc, nullptr, 64, (long)N_NODES * 64, nullptr, 0, 512);
    dt_k<<<dim3(ew, EB), 256, 0, stream>>>(dbc, dt_w, dt_b, dtb, e0);
    scanA_k<<<dim3(NCHUNK, EB), 512, 0, stream>>>(dtb, xs_bf, dbc, A_log, Qb, dtsum, e0);
    scanB_k<<<dim3((D * DSTATE) / 256, EB), 256, 0, stream>>>(Qb, dtsum, A_log, Hin, e0);
    scanC_k<<<dim3(NCHUNK, EB), 512, 0, stream>>>(dtb, xs_bf, dbc, A_log, Hin, xz, Dp,
                                                  ubuf_bf, e0);
    mm_k<4, 2><<<dim3(4, 32, EB), 256, 0, stream>>>(
        ubuf_bf, 512, (long)ND, outwt + (size_t)e0 * 512 * 512, 512, (long)512 * 512,
        nullptr, hattn, nullptr, 512, 0, gate, e0, 512);
  }

  // ---- attn BN, combine, FFN, final BN ----
  bn_stats_k<<<D, 256, 0, stream>>>(x, hattn, mu, rsig);
  bn_norm_k<<<ew, 256, 0, stream>>>(x, hattn, mu, rsig, bn1a_g, bn1a_b, hattn);
  addcvt2_k<<<ew, 256, 0, stream>>>(hlocal, hattn, hcomb, hcomb_bf, nelem);
  mm_k<4, 1><<<dim3(8, 32, 1), 256, 0, stream>>>(hcomb_bf, 512, 0, ffw1t, 512, 0, ff_b1,
                                                 nullptr, ffh_bf, 1024, 0, nullptr, 0, 512);
  mm_k<4, 0><<<dim3(4, 32, 1), 256, 0, stream>>>(ffh_bf, 1024, 0, ffw2t, 1024, 0, ff_b2,
                                                 ffo, nullptr, 512, 0, nullptr, 0, 1024);
  bn_stats_k<<<D, 256, 0, stream>>>(hcomb, ffo, mu, rsig);
  bn_norm_k<<<ew, 256, 0, stream>>>(hcomb, ffo, mu, rsig, bn2_g, bn2_b, out);
}

// Round 6
// 572.160 us; speedup vs baseline: 3.7119x; 1.0342x over previous
//
#include <hip/hip_runtime.h>
#include <hip/hip_bf16.h>
#include <math.h>

#define N_NODES 4096
#define E_EDGE 65536
#define D 512
#define NEXP 4
#define DSTATE 16
#define DCONV 4
#define DTRANK 32
#define EPS 1e-5f
#define LCHUNK 32
#define NCHUNK (N_NODES / LCHUNK)

typedef __hip_bfloat16 bf16;
typedef short bf16x8 __attribute__((ext_vector_type(8)));
typedef float f32x4 __attribute__((ext_vector_type(4)));

__device__ __forceinline__ float siluf(float x) { return x / (1.f + __expf(-x)); }
__device__ __forceinline__ float softplusf(float x) {
  return (x > 20.f) ? x : log1pf(__expf(x));
}

// async global->LDS, 16B per lane; lds dest must be wave-uniform base (HW adds lane*16)
__device__ __forceinline__ void gload16(const void* g, void* l) {
  __builtin_amdgcn_global_load_lds(
      (const __attribute__((address_space(1))) void*)g,
      (__attribute__((address_space(3))) void*)l, 16, 0, 0);
}

// ---------------- MFMA bf16 GEMM ------------------------------------------
// C(MxN) = A(MxK) @ Bt(NxK)^T. A,Bt bf16 row-major (lda/ldb elems, both %8==0).
// BM=128, BN=FN*32, 256 thr = 4 waves (2x2), wave tile 64 x FN*16, BK=32.
// EPI 0: C=A@B(+bias); EPI 1: relu(+bias); EPI 2: Cf[..] atomicAdd gate-scaled.
template <int FN, int EPI>
__global__ __launch_bounds__(256, 2) void mm_k(
    const bf16* __restrict__ A, int lda, long sA,
    const bf16* __restrict__ Bt, int ldb, long sB,
    const float* __restrict__ bias,
    float* __restrict__ Cf, bf16* __restrict__ Cb, int ldc, long sC,
    const float* __restrict__ gate, int ge, int K) {
  constexpr int BN = FN * 32;
  __shared__ __align__(16) bf16 As[128 * 32];
  __shared__ __align__(16) bf16 Bs[BN * 32];
  const int z = blockIdx.z;
  A += (size_t)z * sA;
  Bt += (size_t)z * sB;
  const int tid = threadIdx.x;
  const int w = tid >> 6, l = tid & 63;
  const int wr = w >> 1, wc = w & 1;
  const int bm = blockIdx.y * 128, bn = blockIdx.x * BN;

  f32x4 acc[4][FN];
#pragma unroll
  for (int i = 0; i < 4; ++i)
#pragma unroll
    for (int j = 0; j < FN; ++j) acc[i][j] = 0.f;

  const int srow = l >> 2, schunk = l & 3;
  const bf16* gA = A + (size_t)(bm + w * 16 + srow) * lda + schunk * 8;
  const bf16* gB = Bt + (size_t)(bn + w * 16 + srow) * ldb + schunk * 8;
  bf16* lA = As + w * 512;
  bf16* lB = Bs + w * 512;

  const int ar = wr * 64 + (l & 15);
  const int br = wc * FN * 16 + (l & 15);
  const int kb = l >> 4;

  for (int k0 = 0; k0 < K; k0 += 32) {
    gload16(gA + k0, lA);
    gload16(gA + k0 + (size_t)64 * lda, lA + 64 * 32);
    gload16(gB + k0, lB);
    if (FN == 4) gload16(gB + k0 + (size_t)64 * ldb, lB + 64 * 32);
    __syncthreads();
    const bf16x8* Ap = (const bf16x8*)As;
    const bf16x8* Bp = (const bf16x8*)Bs;
    bf16x8 af[4], bfr[FN];
#pragma unroll
    for (int i = 0; i < 4; ++i) af[i] = Ap[(ar + i * 16) * 4 + kb];
#pragma unroll
    for (int j = 0; j < FN; ++j) bfr[j] = Bp[(br + j * 16) * 4 + kb];
#pragma unroll
    for (int i = 0; i < 4; ++i)
#pragma unroll
      for (int j = 0; j < FN; ++j)
        acc[i][j] = __builtin_amdgcn_mfma_f32_16x16x32_bf16(af[i], bfr[j], acc[i][j], 0, 0, 0);
    __syncthreads();
  }

  if (Cf) Cf += (size_t)z * sC;
  if (Cb) Cb += (size_t)z * sC;
  const int r0 = bm + wr * 64 + (l >> 4) * 4;
  const int c0 = bn + wc * FN * 16 + (l & 15);
#pragma unroll
  for (int i = 0; i < 4; ++i)
#pragma unroll
    for (int j = 0; j < FN; ++j) {
      const int col = c0 + j * 16;
      const float bv = bias ? bias[col] : 0.f;
#pragma unroll
      for (int r = 0; r < 4; ++r) {
        const int row = r0 + i * 16 + r;
        float v = acc[i][j][r] + bv;
        if (EPI == 1) v = fmaxf(v, 0.f);
        if (EPI == 2) {
          atomicAdd(&Cf[(size_t)row * ldc + col], gate[row * NEXP + ge + z] * v);
        } else {
          if (Cf) Cf[(size_t)row * ldc + col] = v;
          if (Cb) Cb[(size_t)row * ldc + col] = __float2bfloat16(v);
        }
      }
    }
}

// ---------------- weight transpose+convert: in[K][N] f32 -> out[N][K] bf16 --
__global__ __launch_bounds__(256) void wtrans_k(const float* __restrict__ in,
                                                bf16* __restrict__ out, int K, int N) {
  __shared__ float t[32][33];
  const size_t zo = (size_t)blockIdx.z * K * N;
  in += zo;
  out += zo;
  const int n0 = blockIdx.x * 32, k0 = blockIdx.y * 32;
  const int tx = threadIdx.x & 31, ty = threadIdx.x >> 5;
  for (int i = ty; i < 32; i += 8) t[i][tx] = in[(size_t)(k0 + i) * N + n0 + tx];
  __syncthreads();
  for (int i = ty; i < 32; i += 8)
    out[(size_t)(n0 + i) * K + k0 + tx] = __float2bfloat16(t[tx][i]);
}

// ---------------- small elementwise kernels --------------------------------
__global__ void cvt_k(const float* __restrict__ a, bf16* __restrict__ o, int n) {
  int i = blockIdx.x * blockDim.x + threadIdx.x;
  if (i < n) o[i] = __float2bfloat16(a[i]);
}
__global__ void addcvt2_k(const float* __restrict__ a, const float* __restrict__ b,
                          float* __restrict__ of, bf16* __restrict__ ob, int n) {
  int i = blockIdx.x * blockDim.x + threadIdx.x;
  if (i < n) {
    float v = a[i] + b[i];
    of[i] = v;
    ob[i] = __float2bfloat16(v);
  }
}

// ---------------- CSR build: histogram, prefix scan, scatter ---------------
__global__ void hist_k(const int* __restrict__ ei, int* __restrict__ deg) {
  int e = blockIdx.x * 256 + threadIdx.x;
  if (e < E_EDGE) atomicAdd(&deg[ei[E_EDGE + e]], 1);
}

__global__ __launch_bounds__(1024) void prefix_k(const int* __restrict__ deg,
                                                 int* __restrict__ rowstart) {
  __shared__ int s[1024];
  int t = threadIdx.x;
  int base = t * 4;
  int d0 = deg[base], d1 = deg[base + 1], d2 = deg[base + 2], d3 = deg[base + 3];
  int sum = d0 + d1 + d2 + d3;
  s[t] = sum;
  __syncthreads();
  for (int off = 1; off < 1024; off <<= 1) {
    int v = (t >= off) ? s[t - off] : 0;
    __syncthreads();
    s[t] += v;
    __syncthreads();
  }
  int excl = s[t] - sum;
  rowstart[base] = excl;
  rowstart[base + 1] = excl + d0;
  rowstart[base + 2] = excl + d0 + d1;
  rowstart[base + 3] = excl + d0 + d1 + d2;
}

__global__ void scatter_k(const int* __restrict__ ei, const int* __restrict__ rowstart,
                          int* __restrict__ cnt, int* __restrict__ eid) {
  int e = blockIdx.x * 256 + threadIdx.x;
  if (e < E_EDGE) {
    int dst = ei[E_EDGE + e];
    int slot = rowstart[dst] + atomicAdd(&cnt[dst], 1);
    eid[slot] = e;
  }
}

// gather: per-node sum of relu(x[src]+ea[e]); writes hpre_bf = bf16(x[n]+aggr)
__global__ __launch_bounds__(256) void aggr_gather_k(
    const float* __restrict__ x, const int* __restrict__ ei, const float* __restrict__ ea,
    const int* __restrict__ rowstart, const int* __restrict__ deg,
    const int* __restrict__ eid, bf16* __restrict__ hpre) {
  int n = blockIdx.x;
  int tid = threadIdx.x;
  int beg = rowstart[n];
  int end = beg + deg[n];
  float a0 = 0.f, a1 = 0.f;
  int i = beg;
  for (; i + 1 < end; i += 2) {
    int e0 = eid[i], e1 = eid[i + 1];
    int s0 = ei[e0], s1 = ei[e1];
    const float* x0 = x + (size_t)s0 * D;
    const float* e0p = ea + (size_t)e0 * D;
    const float* x1 = x + (size_t)s1 * D;
    const float* e1p = ea + (size_t)e1 * D;
    a0 += fmaxf(x0[tid] + e0p[tid], 0.f) + fmaxf(x1[tid] + e1p[tid], 0.f);
    a1 += fmaxf(x0[tid + 256] + e0p[tid + 256], 0.f) +
          fmaxf(x1[tid + 256] + e1p[tid + 256], 0.f);
  }
  if (i < end) {
    int e0 = eid[i];
    int s0 = ei[e0];
    const float* x0 = x + (size_t)s0 * D;
    const float* e0p = ea + (size_t)e0 * D;
    a0 += fmaxf(x0[tid] + e0p[tid], 0.f);
    a1 += fmaxf(x0[tid + 256] + e0p[tid + 256], 0.f);
  }
  const float* xn = x + (size_t)n * D;
  hpre[(size_t)n * D + tid] = __float2bfloat16(xn[tid] + a0);
  hpre[(size_t)n * D + tid + 256] = __float2bfloat16(xn[tid + 256] + a1);
}

// ---------------- gate second layer + softmax ------------------------------
__global__ __launch_bounds__(256) void gate2_k(const float* __restrict__ g1,
                                               const float* __restrict__ w2,
                                               const float* __restrict__ b2,
                                               float* __restrict__ gate) {
  int row = blockIdx.x * 4 + (threadIdx.x >> 6);
  int lane = threadIdx.x & 63;
  float a0 = 0.f, a1 = 0.f, a2 = 0.f, a3 = 0.f;
  for (int k = lane; k < 256; k += 64) {
    float v = g1[(size_t)row * 256 + k];
    a0 = fmaf(v, w2[k * 4 + 0], a0);
    a1 = fmaf(v, w2[k * 4 + 1], a1);
    a2 = fmaf(v, w2[k * 4 + 2], a2);
    a3 = fmaf(v, w2[k * 4 + 3], a3);
  }
#pragma unroll
  for (int off = 32; off; off >>= 1) {
    a0 += __shfl_down(a0, off);
    a1 += __shfl_down(a1, off);
    a2 += __shfl_down(a2, off);
    a3 += __shfl_down(a3, off);
  }
  if (lane == 0) {
    float l0 = a0 + b2[0], l1 = a1 + b2[1], l2 = a2 + b2[2], l3 = a3 + b2[3];
    float m = fmaxf(fmaxf(l0, l1), fmaxf(l2, l3));
    float e0 = __expf(l0 - m), e1 = __expf(l1 - m), e2 = __expf(l2 - m), e3 = __expf(l3 - m);
    float s = 1.f / (e0 + e1 + e2 + e3);
    gate[row * 4 + 0] = e0 * s;
    gate[row * 4 + 1] = e1 * s;
    gate[row * 4 + 2] = e2 * s;
    gate[row * 4 + 3] = e3 * s;
  }
}

// ---------------- causal depthwise conv + silu -> bf16 (xz is bf16) --------
__global__ void conv_silu_k(const bf16* __restrict__ xz, const float* __restrict__ cw,
                            const float* __restrict__ cb, bf16* __restrict__ xs, int e0) {
  const int z = blockIdx.y;
  xz += (size_t)z * N_NODES * 2 * D;
  xs += (size_t)z * N_NODES * D;
  cw += (size_t)(e0 + z) * D * DCONV;
  cb += (size_t)(e0 + z) * D;
  int idx = blockIdx.x * blockDim.x + threadIdx.x;
  if (idx >= N_NODES * D) return;
  int t = idx >> 9;
  int d = idx & (D - 1);
  float acc = cb[d];
#pragma unroll
  for (int k = 0; k < DCONV; ++k) {
    int tt = t + k - (DCONV - 1);
    if (tt >= 0)
      acc = fmaf(cw[d * DCONV + k], __bfloat162float(xz[(size_t)tt * (2 * D) + d]), acc);
  }
  xs[idx] = __float2bfloat16(siluf(acc));
}

// ---------------- fused dt: softplus(dbc[:, :32] @ dt_w + dt_b) -> bf16 ----
__global__ void dt_k(const float* __restrict__ dbc, const float* __restrict__ dtw,
                     const float* __restrict__ dtbias, bf16* __restrict__ dt, int e0) {
  const int z = blockIdx.y;
  dbc += (size_t)z * N_NODES * 64;
  dt += (size_t)z * N_NODES * D;
  dtw += (size_t)(e0 + z) * DTRANK * D;
  dtbias += (size_t)(e0 + z) * D;
  int idx = blockIdx.x * blockDim.x + threadIdx.x;
  int t = idx >> 9, d = idx & (D - 1);
  float acc = dtbias[d];
#pragma unroll
  for (int k = 0; k < DTRANK; ++k) acc = fmaf(dbc[t * 64 + k], dtw[k * D + d], acc);
  dt[idx] = __float2bfloat16(softplusf(acc));
}

// ---------------- BN stats / norm ------------------------------------------
__global__ __launch_bounds__(256) void bn_stats_k(const float* __restrict__ p,
                                                  const float* __restrict__ q,
                                                  float* __restrict__ mu,
                                                  float* __restrict__ rsig) {
  int d = blockIdx.x;
  float s = 0.f, s2 = 0.f;
  for (int r = threadIdx.x; r < N_NODES; r += 256) {
    float v = p[(size_t)r * D + d] + q[(size_t)r * D + d];
    s += v;
    s2 = fmaf(v, v, s2);
  }
  __shared__ float sh[256], sh2[256];
  sh[threadIdx.x] = s;
  sh2[threadIdx.x] = s2;
  __syncthreads();
  for (int off = 128; off; off >>= 1) {
    if (threadIdx.x < off) {
      sh[threadIdx.x] += sh[threadIdx.x + off];
      sh2[threadIdx.x] += sh2[threadIdx.x + off];
    }
    __syncthreads();
  }
  if (threadIdx.x == 0) {
    float m = sh[0] / N_NODES;
    float var = sh2[0] / N_NODES - m * m;
    mu[d] = m;
    rsig[d] = rsqrtf(var + EPS);
  }
}

__global__ void bn_norm_k(const float* __restrict__ p, const float* __restrict__ q,
                          const float* __restrict__ mu, const float* __restrict__ rsig,
                          const float* __restrict__ g, const float* __restrict__ b,
                          float* __restrict__ o) {
  int idx = blockIdx.x * blockDim.x + threadIdx.x;
  if (idx >= N_NODES * D) return;
  int d = idx & (D - 1);
  o[idx] = (p[idx] + q[idx] - mu[d]) * rsig[d] * g[d] + b[d];
}

// ---------------- chunked selective scan -----------------------------------
__global__ __launch_bounds__(512) void scanA_k(const bf16* __restrict__ dt,
                                               const bf16* __restrict__ xs,
                                               const float* __restrict__ dbc,
                                               const float* __restrict__ Alog,
                                               float* __restrict__ Q,
                                               float* __restrict__ dtsum, int e0) {
  const int z = blockIdx.y;
  dt += (size_t)z * N_NODES * D;
  xs += (size_t)z * N_NODES * D;
  dbc += (size_t)z * N_NODES * 64;
  Alog += (size_t)(e0 + z) * D * DSTATE;
  Q += (size_t)z * NCHUNK * D * DSTATE;
  dtsum += (size_t)z * NCHUNK * D;
  int c = blockIdx.x;
  int d = threadIdx.x;
  float As[DSTATE], h[DSTATE];
#pragma unroll
  for (int s = 0; s < DSTATE; ++s) {
    As[s] = -__expf(Alog[d * DSTATE + s]);
    h[s] = 0.f;
  }
  float dts = 0.f;
  int t0 = c * LCHUNK;
  for (int t = t0; t < t0 + LCHUNK; ++t) {
    float dtv = __bfloat162float(dt[(size_t)t * D + d]);
    float xv = __bfloat162float(xs[(size_t)t * D + d]);
    float bx = dtv * xv;
    dts += dtv;
#pragma unroll
    for (int s = 0; s < DSTATE; ++s) {
      float Bv = dbc[(size_t)t * 64 + DTRANK + s];
      h[s] = fmaf(__expf(dtv * As[s]), h[s], bx * Bv);
    }
  }
  size_t base = ((size_t)c * D + d) * DSTATE;
#pragma unroll
  for (int s = 0; s < DSTATE; ++s) Q[base + s] = h[s];
  dtsum[c * D + d] = dts;
}

__global__ __launch_bounds__(256) void scanB_k(const float* __restrict__ Q,
                                               const float* __restrict__ dtsum,
                                               const float* __restrict__ Alog,
                                               float* __restrict__ Hin, int e0) {
  const int z = blockIdx.y;
  Q += (size_t)z * NCHUNK * D * DSTATE;
  dtsum += (size_t)z * NCHUNK * D;
  Alog += (size_t)(e0 + z) * D * DSTATE;
  Hin += (size_t)z * NCHUNK * D * DSTATE;
  int idx = blockIdx.x * blockDim.x + threadIdx.x;  // d*DSTATE + s
  int d = idx >> 4;
  float As = -__expf(Alog[idx]);
  float h = 0.f;
  for (int c = 0; c < NCHUNK; ++c) {
    size_t base = (size_t)c * D * DSTATE + idx;
    Hin[base] = h;
    h = fmaf(__expf(As * dtsum[c * D + d]), h, Q[base]);
  }
}

__global__ __launch_bounds__(512) void scanC_k(const bf16* __restrict__ dt,
                                               const bf16* __restrict__ xs,
                                               const float* __restrict__ dbc,
                                               const float* __restrict__ Alog,
                                               const float* __restrict__ Hin,
                                               const bf16* __restrict__ xz,
                                               const float* __restrict__ Dp,
                                               bf16* __restrict__ u, int e0) {
  const int z = blockIdx.y;
  dt += (size_t)z * N_NODES * D;
  xs += (size_t)z * N_NODES * D;
  dbc += (size_t)z * N_NODES * 64;
  Alog += (size_t)(e0 + z) * D * DSTATE;
  Hin += (size_t)z * NCHUNK * D * DSTATE;
  xz += (size_t)z * N_NODES * 2 * D;
  Dp += (size_t)(e0 + z) * D;
  u += (size_t)z * N_NODES * D;
  int c = blockIdx.x;
  int d = threadIdx.x;
  float As[DSTATE], h[DSTATE];
  size_t base = ((size_t)c * D + d) * DSTATE;
#pragma unroll
  for (int s = 0; s < DSTATE; ++s) {
    As[s] = -__expf(Alog[d * DSTATE + s]);
    h[s] = Hin[base + s];
  }
  float Dv = Dp[d];
  int t0 = c * LCHUNK;
  for (int t = t0; t < t0 + LCHUNK; ++t) {
    float dtv = __bfloat162float(dt[(size_t)t * D + d]);
    float xv = __bfloat162float(xs[(size_t)t * D + d]);
    float bx = dtv * xv;
    float y = 0.f;
#pragma unroll
    for (int s = 0; s < DSTATE; ++s) {
      float Bv = dbc[(size_t)t * 64 + DTRANK + s];
      float Cv = dbc[(size_t)t * 64 + DTRANK + DSTATE + s];
      h[s] = fmaf(__expf(dtv * As[s]), h[s], bx * Bv);
      y = fmaf(h[s], Cv, y);
    }
    float zv = __bfloat162float(xz[(size_t)t * (2 * D) + D + d]);
    u[(size_t)t * D + d] = __float2bfloat16((y + Dv * xv) * siluf(zv));
  }
}

extern "C" void kernel_launch(void* const* d_in, const int* in_sizes, int n_in,
                              void* d_out, int out_size, void* d_ws, size_t ws_size,
                              hipStream_t stream) {
  const float* x = (const float*)d_in[0];
  const int* ei = (const int*)d_in[1];
  const float* ea = (const float*)d_in[2];
  const float* gin_w1 = (const float*)d_in[3];
  const float* gin_b1 = (const float*)d_in[4];
  const float* gin_w2 = (const float*)d_in[5];
  const float* gin_b2 = (const float*)d_in[6];
  const float* bn1l_g = (const float*)d_in[7];
  const float* bn1l_b = (const float*)d_in[8];
  const float* bn1a_g = (const float*)d_in[9];
  const float* bn1a_b = (const float*)d_in[10];
  const float* bn2_g = (const float*)d_in[11];
  const float* bn2_b = (const float*)d_in[12];
  const float* gate_w1 = (const float*)d_in[13];
  const float* gate_b1 = (const float*)d_in[14];
  const float* gate_w2 = (const float*)d_in[15];
  const float* gate_b2 = (const float*)d_in[16];
  const float* in_w = (const float*)d_in[17];
  const float* conv_w = (const float*)d_in[18];
  const float* conv_b = (const float*)d_in[19];
  const float* x_w = (const float*)d_in[20];
  const float* dt_w = (const float*)d_in[21];
  const float* dt_b = (const float*)d_in[22];
  const float* A_log = (const float*)d_in[23];
  const float* Dp = (const float*)d_in[24];
  const float* out_w = (const float*)d_in[25];
  const float* ff_w1 = (const float*)d_in[26];
  const float* ff_b1 = (const float*)d_in[27];
  const float* ff_w2 = (const float*)d_in[28];
  const float* ff_b2 = (const float*)d_in[29];
  float* out = (float*)d_out;

  const size_t ND = (size_t)N_NODES * D;  // 2M elems
  const size_t NDb = ND / 2;              // bf16 buffer in float units

  const size_t fixed_f = 3 * ND + (size_t)N_NODES * 256 + 16384 + 2490624 + ND + 2048 + 81920;
  const size_t per_f = 2 * ND + NDb + (size_t)N_NODES * 64 + ND +
                       2 * (size_t)NCHUNK * D * DSTATE + (size_t)NCHUNK * D + NDb;
  const int EB = (ws_size >= (fixed_f + 4 * per_f + 65536) * sizeof(float)) ? 4 : 1;

  float* ws = (float*)d_ws;
  size_t off = 0;
  auto alloc = [&](size_t n) {
    float* p = ws + off;
    off += (n + 63) & ~(size_t)63;
    return p;
  };
  float* aggr = alloc(ND);     // only used as ffo in phase 4 now
  float* pbuf = alloc(ND);     // hpre_bf + t1_bf; later: ffh_bf
  float* hlocal = alloc(ND);
  float* g1 = alloc((size_t)N_NODES * 256);
  float* gate = alloc((size_t)N_NODES * NEXP);
  bf16* gw1t = (bf16*)alloc(131072);
  bf16* gw2t = (bf16*)alloc(131072);
  bf16* gatew1t = (bf16*)alloc(65536);
  bf16* inwt = (bf16*)alloc(1048576);
  bf16* xwt = (bf16*)alloc(65536);
  bf16* outwt = (bf16*)alloc(524288);
  bf16* ffw1t = (bf16*)alloc(262144);
  bf16* ffw2t = (bf16*)alloc(262144);
  // CSR buffers (1 int == 1 float == 4B, alloc() counts elements)
  int* deg = (int*)alloc(N_NODES);       // 4096 ints
  int* eid = (int*)alloc(E_EDGE);        // 65536 ints
  int* cnt = (int*)alloc(N_NODES);       // 4096 ints
  int* rowstart = (int*)alloc(N_NODES);  // 4096 ints
  float* xbf_f = alloc(NDb);
  float* xz_f = alloc((size_t)EB * ND);    // bf16 xz (EB * 4096 * 1024); later: hcomb fp32
  float* xs_f = alloc((size_t)EB * NDb);
  float* dbc = alloc((size_t)EB * N_NODES * 64);
  float* dtb_f = alloc((size_t)EB * NDb);  // bf16 dt
  float* Qb = alloc((size_t)EB * NCHUNK * D * DSTATE);
  float* Hin = alloc((size_t)EB * NCHUNK * D * DSTATE);
  float* dtsum = alloc((size_t)EB * NCHUNK * D);
  float* ubuf_f = alloc((size_t)EB * NDb);  // later: hcomb_bf
  float* hattn = alloc(ND);
  float* mu = alloc(D);
  float* rsig = alloc(D);

  bf16* x_bf = (bf16*)xbf_f;
  bf16* hpre_bf = (bf16*)pbuf;
  bf16* t1_bf = (bf16*)(pbuf + NDb);
  bf16* xz_bf = (bf16*)xz_f;
  bf16* xs_bf = (bf16*)xs_f;
  bf16* dt_bf = (bf16*)dtb_f;
  bf16* ubuf_bf = (bf16*)ubuf_f;
  // phase-4 aliases (source buffers dead by then)
  float* hcomb = xz_f;                // ND fp32 <= EB*ND
  bf16* hcomb_bf = (bf16*)ubuf_f;     // NDb floats available
  bf16* ffh_bf = (bf16*)pbuf;         // 4096x1024 bf16 = 2M floats = ND
  float* ffo = aggr;

  const int nelem = N_NODES * D;
  const int ew = (nelem + 255) / 256;

  hipMemsetAsync(deg, 0, N_NODES * sizeof(int), stream);
  hipMemsetAsync(cnt, 0, N_NODES * sizeof(int), stream);
  hipMemsetAsync(hattn, 0, ND * sizeof(float), stream);

  // ---- weight transposes (f32 [K][N] -> bf16 [N][K]) ----
  wtrans_k<<<dim3(16, 16, 1), 256, 0, stream>>>(gin_w1, gw1t, 512, 512);
  wtrans_k<<<dim3(16, 16, 1), 256, 0, stream>>>(gin_w2, gw2t, 512, 512);
  wtrans_k<<<dim3(8, 16, 1), 256, 0, stream>>>(gate_w1, gatew1t, 512, 256);
  wtrans_k<<<dim3(32, 16, 4), 256, 0, stream>>>(in_w, inwt, 512, 1024);
  wtrans_k<<<dim3(2, 16, 4), 256, 0, stream>>>(x_w, xwt, 512, 64);
  wtrans_k<<<dim3(16, 16, 4), 256, 0, stream>>>(out_w, outwt, 512, 512);
  wtrans_k<<<dim3(32, 16, 1), 256, 0, stream>>>(ff_w1, ffw1t, 512, 1024);
  wtrans_k<<<dim3(16, 32, 1), 256, 0, stream>>>(ff_w2, ffw2t, 1024, 512);
  cvt_k<<<ew, 256, 0, stream>>>(x, x_bf, nelem);

  // ---- CSR build + GIN local branch ----
  hist_k<<<E_EDGE / 256, 256, 0, stream>>>(ei, deg);
  prefix_k<<<1, 1024, 0, stream>>>(deg, rowstart);
  scatter_k<<<E_EDGE / 256, 256, 0, stream>>>(ei, rowstart, cnt, eid);
  aggr_gather_k<<<N_NODES, 256, 0, stream>>>(x, ei, ea, rowstart, deg, eid, hpre_bf);
  mm_k<2, 1><<<dim3(8, 32, 1), 256, 0, stream>>>(hpre_bf, 512, 0, gw1t, 512, 0, gin_b1,
                                                 nullptr, t1_bf, 512, 0, nullptr, 0, 512);
  mm_k<2, 0><<<dim3(8, 32, 1), 256, 0, stream>>>(t1_bf, 512, 0, gw2t, 512, 0, gin_b2,
                                                 hlocal, nullptr, 512, 0, nullptr, 0, 512);
  bn_stats_k<<<D, 256, 0, stream>>>(x, hlocal, mu, rsig);
  bn_norm_k<<<ew, 256, 0, stream>>>(x, hlocal, mu, rsig, bn1l_g, bn1l_b, hlocal);

  // ---- gate ----
  mm_k<2, 1><<<dim3(4, 32, 1), 256, 0, stream>>>(x_bf, 512, 0, gatew1t, 512, 0, gate_b1,
                                                 g1, nullptr, 256, 0, nullptr, 0, 512);
  gate2_k<<<N_NODES / 4, 256, 0, stream>>>(g1, gate_w2, gate_b2, gate);

  // ---- experts (z-batched by EB) ----
  for (int e0 = 0; e0 < NEXP; e0 += EB) {
    mm_k<4, 0><<<dim3(8, 32, EB), 256, 0, stream>>>(
        x_bf, 512, 0, inwt + (size_t)e0 * 512 * 1024, 512, (long)512 * 1024, nullptr,
        nullptr, xz_bf, 1024, (long)N_NODES * 1024, nullptr, 0, 512);
    conv_silu_k<<<dim3(ew, EB), 256, 0, stream>>>(xz_bf, conv_w, conv_b, xs_bf, e0);
    mm_k<2, 0><<<dim3(1, 32, EB), 256, 0, stream>>>(
        xs_bf, 512, (long)ND, xwt + (size_t)e0 * 64 * 512, 512, (long)64 * 512, nullptr,
        dbc, nullptr, 64, (long)N_NODES * 64, nullptr, 0, 512);
    dt_k<<<dim3(ew, EB), 256, 0, stream>>>(dbc, dt_w, dt_b, dt_bf, e0);
    scanA_k<<<dim3(NCHUNK, EB), 512, 0, stream>>>(dt_bf, xs_bf, dbc, A_log, Qb, dtsum, e0);
    scanB_k<<<dim3((D * DSTATE) / 256, EB), 256, 0, stream>>>(Qb, dtsum, A_log, Hin, e0);
    scanC_k<<<dim3(NCHUNK, EB), 512, 0, stream>>>(dt_bf, xs_bf, dbc, A_log, Hin, xz_bf, Dp,
                                                  ubuf_bf, e0);
    mm_k<4, 2><<<dim3(4, 32, EB), 256, 0, stream>>>(
        ubuf_bf, 512, (long)ND, outwt + (size_t)e0 * 512 * 512, 512, (long)512 * 512,
        nullptr, hattn, nullptr, 512, 0, gate, e0, 512);
  }

  // ---- attn BN, combine, FFN, final BN ----
  bn_stats_k<<<D, 256, 0, stream>>>(x, hattn, mu, rsig);
  bn_norm_k<<<ew, 256, 0, stream>>>(x, hattn, mu, rsig, bn1a_g, bn1a_b, hattn);
  addcvt2_k<<<ew, 256, 0, stream>>>(hlocal, hattn, hcomb, hcomb_bf, nelem);
  mm_k<4, 1><<<dim3(8, 32, 1), 256, 0, stream>>>(hcomb_bf, 512, 0, ffw1t, 512, 0, ff_b1,
                                                 nullptr, ffh_bf, 1024, 0, nullptr, 0, 512);
  mm_k<2, 0><<<dim3(8, 32, 1), 256, 0, stream>>>(ffh_bf, 1024, 0, ffw2t, 1024, 0, ff_b2,
                                                 ffo, nullptr, 512, 0, nullptr, 0, 1024);
  bn_stats_k<<<D, 256, 0, stream>>>(hcomb, ffo, mu, rsig);
  bn_norm_k<<<ew, 256, 0, stream>>>(hcomb, ffo, mu, rsig, bn2_g, bn2_b, out);
}

// Round 7
// 493.885 us; speedup vs baseline: 4.3002x; 1.1585x over previous
//
#include <hip/hip_runtime.h>
#include <hip/hip_bf16.h>
#include <math.h>

#define N_NODES 4096
#define E_EDGE 65536
#define D 512
#define NEXP 4
#define DSTATE 16
#define DCONV 4
#define DTRANK 32
#define EPS 1e-5f
#define LCHUNK 32
#define NCHUNK (N_NODES / LCHUNK)

typedef __hip_bfloat16 bf16;
typedef short bf16x8 __attribute__((ext_vector_type(8)));
typedef float f32x4 __attribute__((ext_vector_type(4)));

__device__ __forceinline__ float siluf(float x) { return x / (1.f + __expf(-x)); }
__device__ __forceinline__ float softplusf(float x) {
  return (x > 20.f) ? x : log1pf(__expf(x));
}

// async global->LDS, 16B per lane; lds dest must be wave-uniform base (HW adds lane*16)
__device__ __forceinline__ void gload16(const void* g, void* l) {
  __builtin_amdgcn_global_load_lds(
      (const __attribute__((address_space(1))) void*)g,
      (__attribute__((address_space(3))) void*)l, 16, 0, 0);
}

// ---------------- MFMA bf16 GEMM ------------------------------------------
// C(MxN) = A(MxK) @ Bt(NxK)^T. A,Bt bf16 row-major (lda/ldb elems, both %8==0).
// BM=128, BN=FN*32, 256 thr = 4 waves (2x2), wave tile 64 x FN*16, BK=32.
// EPI 0: C=A@B(+bias); EPI 1: relu(+bias).
template <int FN, int EPI>
__global__ __launch_bounds__(256, 2) void mm_k(
    const bf16* __restrict__ A, int lda, long sA,
    const bf16* __restrict__ Bt, int ldb, long sB,
    const float* __restrict__ bias,
    float* __restrict__ Cf, bf16* __restrict__ Cb, int ldc, long sC, int K) {
  constexpr int BN = FN * 32;
  __shared__ __align__(16) bf16 As[128 * 32];
  __shared__ __align__(16) bf16 Bs[BN * 32];
  const int z = blockIdx.z;
  A += (size_t)z * sA;
  Bt += (size_t)z * sB;
  const int tid = threadIdx.x;
  const int w = tid >> 6, l = tid & 63;
  const int wr = w >> 1, wc = w & 1;
  const int bm = blockIdx.y * 128, bn = blockIdx.x * BN;

  f32x4 acc[4][FN];
#pragma unroll
  for (int i = 0; i < 4; ++i)
#pragma unroll
    for (int j = 0; j < FN; ++j) acc[i][j] = 0.f;

  const int srow = l >> 2, schunk = l & 3;
  const bf16* gA = A + (size_t)(bm + w * 16 + srow) * lda + schunk * 8;
  const bf16* gB = Bt + (size_t)(bn + w * 16 + srow) * ldb + schunk * 8;
  bf16* lA = As + w * 512;
  bf16* lB = Bs + w * 512;

  const int ar = wr * 64 + (l & 15);
  const int br = wc * FN * 16 + (l & 15);
  const int kb = l >> 4;

  for (int k0 = 0; k0 < K; k0 += 32) {
    gload16(gA + k0, lA);
    gload16(gA + k0 + (size_t)64 * lda, lA + 64 * 32);
    gload16(gB + k0, lB);
    if (FN == 4) gload16(gB + k0 + (size_t)64 * ldb, lB + 64 * 32);
    __syncthreads();
    const bf16x8* Ap = (const bf16x8*)As;
    const bf16x8* Bp = (const bf16x8*)Bs;
    bf16x8 af[4], bfr[FN];
#pragma unroll
    for (int i = 0; i < 4; ++i) af[i] = Ap[(ar + i * 16) * 4 + kb];
#pragma unroll
    for (int j = 0; j < FN; ++j) bfr[j] = Bp[(br + j * 16) * 4 + kb];
#pragma unroll
    for (int i = 0; i < 4; ++i)
#pragma unroll
      for (int j = 0; j < FN; ++j)
        acc[i][j] = __builtin_amdgcn_mfma_f32_16x16x32_bf16(af[i], bfr[j], acc[i][j], 0, 0, 0);
    __syncthreads();
  }

  if (Cf) Cf += (size_t)z * sC;
  if (Cb) Cb += (size_t)z * sC;
  const int r0 = bm + wr * 64 + (l >> 4) * 4;
  const int c0 = bn + wc * FN * 16 + (l & 15);
#pragma unroll
  for (int i = 0; i < 4; ++i)
#pragma unroll
    for (int j = 0; j < FN; ++j) {
      const int col = c0 + j * 16;
      const float bv = bias ? bias[col] : 0.f;
#pragma unroll
      for (int r = 0; r < 4; ++r) {
        const int row = r0 + i * 16 + r;
        float v = acc[i][j][r] + bv;
        if (EPI == 1) v = fmaxf(v, 0.f);
        if (Cf) Cf[(size_t)row * ldc + col] = v;
        if (Cb) Cb[(size_t)row * ldc + col] = __float2bfloat16(v);
      }
    }
}

// -------- weight transpose+convert: in[K][N] f32 -> out[N][K] bf16 (ld ldo) --
__global__ __launch_bounds__(256) void wtrans_k(const float* __restrict__ in,
                                                bf16* __restrict__ out, int K, int N,
                                                int ldo, long s_in, long s_out) {
  __shared__ float t[32][33];
  in += (size_t)blockIdx.z * s_in;
  out += (size_t)blockIdx.z * s_out;
  const int n0 = blockIdx.x * 32, k0 = blockIdx.y * 32;
  const int tx = threadIdx.x & 31, ty = threadIdx.x >> 5;
  for (int i = ty; i < 32; i += 8) t[i][tx] = in[(size_t)(k0 + i) * N + n0 + tx];
  __syncthreads();
  for (int i = ty; i < 32; i += 8)
    out[(size_t)(n0 + i) * ldo + k0 + tx] = __float2bfloat16(t[tx][i]);
}

// ---------------- CSR build: histogram, prefix scan, scatter ---------------
__global__ void hist_k(const int* __restrict__ ei, int* __restrict__ deg) {
  int e = blockIdx.x * 256 + threadIdx.x;
  if (e < E_EDGE) atomicAdd(&deg[ei[E_EDGE + e]], 1);
}

__global__ __launch_bounds__(1024) void prefix_k(const int* __restrict__ deg,
                                                 int* __restrict__ rowstart) {
  __shared__ int s[1024];
  int t = threadIdx.x;
  int base = t * 4;
  int d0 = deg[base], d1 = deg[base + 1], d2 = deg[base + 2], d3 = deg[base + 3];
  int sum = d0 + d1 + d2 + d3;
  s[t] = sum;
  __syncthreads();
  for (int off = 1; off < 1024; off <<= 1) {
    int v = (t >= off) ? s[t - off] : 0;
    __syncthreads();
    s[t] += v;
    __syncthreads();
  }
  int excl = s[t] - sum;
  rowstart[base] = excl;
  rowstart[base + 1] = excl + d0;
  rowstart[base + 2] = excl + d0 + d1;
  rowstart[base + 3] = excl + d0 + d1 + d2;
}

__global__ void scatter_k(const int* __restrict__ ei, const int* __restrict__ rowstart,
                          int* __restrict__ cnt, int* __restrict__ eid) {
  int e = blockIdx.x * 256 + threadIdx.x;
  if (e < E_EDGE) {
    int dst = ei[E_EDGE + e];
    int slot = rowstart[dst] + atomicAdd(&cnt[dst], 1);
    eid[slot] = e;
  }
}

// gather: per-node sum of relu(x[src]+ea[e]); writes hpre_bf and x_bf
__global__ __launch_bounds__(256) void aggr_gather_k(
    const float* __restrict__ x, const int* __restrict__ ei, const float* __restrict__ ea,
    const int* __restrict__ rowstart, const int* __restrict__ deg,
    const int* __restrict__ eid, bf16* __restrict__ hpre, bf16* __restrict__ xbf) {
  int n = blockIdx.x;
  int tid = threadIdx.x;
  int beg = rowstart[n];
  int end = beg + deg[n];
  float a0 = 0.f, a1 = 0.f;
  int i = beg;
  for (; i + 1 < end; i += 2) {
    int e0 = eid[i], e1 = eid[i + 1];
    int s0 = ei[e0], s1 = ei[e1];
    const float* x0 = x + (size_t)s0 * D;
    const float* e0p = ea + (size_t)e0 * D;
    const float* x1 = x + (size_t)s1 * D;
    const float* e1p = ea + (size_t)e1 * D;
    a0 += fmaxf(x0[tid] + e0p[tid], 0.f) + fmaxf(x1[tid] + e1p[tid], 0.f);
    a1 += fmaxf(x0[tid + 256] + e0p[tid + 256], 0.f) +
          fmaxf(x1[tid + 256] + e1p[tid + 256], 0.f);
  }
  if (i < end) {
    int e0 = eid[i];
    int s0 = ei[e0];
    const float* x0 = x + (size_t)s0 * D;
    const float* e0p = ea + (size_t)e0 * D;
    a0 += fmaxf(x0[tid] + e0p[tid], 0.f);
    a1 += fmaxf(x0[tid + 256] + e0p[tid + 256], 0.f);
  }
  float xv0 = x[(size_t)n * D + tid];
  float xv1 = x[(size_t)n * D + tid + 256];
  hpre[(size_t)n * D + tid] = __float2bfloat16(xv0 + a0);
  hpre[(size_t)n * D + tid + 256] = __float2bfloat16(xv1 + a1);
  xbf[(size_t)n * D + tid] = __float2bfloat16(xv0);
  xbf[(size_t)n * D + tid + 256] = __float2bfloat16(xv1);
}

// ---------------- gate second layer + softmax ------------------------------
__global__ __launch_bounds__(256) void gate2_k(const float* __restrict__ g1,
                                               const float* __restrict__ w2,
                                               const float* __restrict__ b2,
                                               float* __restrict__ gate) {
  int row = blockIdx.x * 4 + (threadIdx.x >> 6);
  int lane = threadIdx.x & 63;
  float a0 = 0.f, a1 = 0.f, a2 = 0.f, a3 = 0.f;
  for (int k = lane; k < 256; k += 64) {
    float v = g1[(size_t)row * 256 + k];
    a0 = fmaf(v, w2[k * 4 + 0], a0);
    a1 = fmaf(v, w2[k * 4 + 1], a1);
    a2 = fmaf(v, w2[k * 4 + 2], a2);
    a3 = fmaf(v, w2[k * 4 + 3], a3);
  }
#pragma unroll
  for (int off = 32; off; off >>= 1) {
    a0 += __shfl_down(a0, off);
    a1 += __shfl_down(a1, off);
    a2 += __shfl_down(a2, off);
    a3 += __shfl_down(a3, off);
  }
  if (lane == 0) {
    float l0 = a0 + b2[0], l1 = a1 + b2[1], l2 = a2 + b2[2], l3 = a3 + b2[3];
    float m = fmaxf(fmaxf(l0, l1), fmaxf(l2, l3));
    float e0 = __expf(l0 - m), e1 = __expf(l1 - m), e2 = __expf(l2 - m), e3 = __expf(l3 - m);
    float s = 1.f / (e0 + e1 + e2 + e3);
    gate[row * 4 + 0] = e0 * s;
    gate[row * 4 + 1] = e1 * s;
    gate[row * 4 + 2] = e2 * s;
    gate[row * 4 + 3] = e3 * s;
  }
}

// ---------------- causal depthwise conv + silu -> bf16 (xz is bf16) --------
__global__ void conv_silu_k(const bf16* __restrict__ xz, const float* __restrict__ cw,
                            const float* __restrict__ cb, bf16* __restrict__ xs, int e0) {
  const int z = blockIdx.y;
  xz += (size_t)z * N_NODES * 2 * D;
  xs += (size_t)z * N_NODES * D;
  cw += (size_t)(e0 + z) * D * DCONV;
  cb += (size_t)(e0 + z) * D;
  int idx = blockIdx.x * blockDim.x + threadIdx.x;
  if (idx >= N_NODES * D) return;
  int t = idx >> 9;
  int d = idx & (D - 1);
  float acc = cb[d];
#pragma unroll
  for (int k = 0; k < DCONV; ++k) {
    int tt = t + k - (DCONV - 1);
    if (tt >= 0)
      acc = fmaf(cw[d * DCONV + k], __bfloat162float(xz[(size_t)tt * (2 * D) + d]), acc);
  }
  xs[idx] = __float2bfloat16(siluf(acc));
}

// ---------------- fused dt: softplus(dbc[:, :32] @ dt_w + dt_b) -> bf16 ----
__global__ void dt_k(const float* __restrict__ dbc, const float* __restrict__ dtw,
                     const float* __restrict__ dtbias, bf16* __restrict__ dt, int e0) {
  const int z = blockIdx.y;
  dbc += (size_t)z * N_NODES * 64;
  dt += (size_t)z * N_NODES * D;
  dtw += (size_t)(e0 + z) * DTRANK * D;
  dtbias += (size_t)(e0 + z) * D;
  int idx = blockIdx.x * blockDim.x + threadIdx.x;
  int t = idx >> 9, d = idx & (D - 1);
  float acc = dtbias[d];
#pragma unroll
  for (int k = 0; k < DTRANK; ++k) acc = fmaf(dbc[t * 64 + k], dtw[k * D + d], acc);
  dt[idx] = __float2bfloat16(softplusf(acc));
}

// ------- column stats: acc[d] += sum(p+q), acc[512+d] += sum((p+q)^2) -------
// grid 64 x 256 thr; coalesced row-major reads; fp32 atomics (ulp-level nondet).
__global__ __launch_bounds__(256) void colstats_k(const float* __restrict__ p,
                                                  const float* __restrict__ q,
                                                  float* __restrict__ acc) {
  __shared__ float sb[4][512], sb2[4][512];
  const int w = threadIdx.x >> 6, l = threadIdx.x & 63;
  float s[8], s2[8];
#pragma unroll
  for (int i = 0; i < 8; ++i) { s[i] = 0.f; s2[i] = 0.f; }
  for (int j = 0; j < 16; ++j) {
    size_t base = ((size_t)blockIdx.x * 64 + w * 16 + j) * D;
#pragma unroll
    for (int i = 0; i < 8; ++i) {
      int c = i * 64 + l;
      float v = p[base + c] + q[base + c];
      s[i] += v;
      s2[i] = fmaf(v, v, s2[i]);
    }
  }
#pragma unroll
  for (int i = 0; i < 8; ++i) {
    sb[w][i * 64 + l] = s[i];
    sb2[w][i * 64 + l] = s2[i];
  }
  __syncthreads();
  for (int c = threadIdx.x; c < 512; c += 256) {
    atomicAdd(&acc[c], sb[0][c] + sb[1][c] + sb[2][c] + sb[3][c]);
    atomicAdd(&acc[512 + c], sb2[0][c] + sb2[1][c] + sb2[2][c] + sb2[3][c]);
  }
}

__device__ __forceinline__ void bn_params(const float* acc, int d, float& mu, float& rsig) {
  mu = acc[d] * (1.f / N_NODES);
  float var = acc[512 + d] * (1.f / N_NODES) - mu * mu;
  rsig = rsqrtf(var + EPS);
}

// o = bn(p+q) (fp32)
__global__ void norm_k(const float* __restrict__ p, const float* __restrict__ q,
                       const float* __restrict__ acc, const float* __restrict__ g,
                       const float* __restrict__ b, float* __restrict__ o) {
  int idx = blockIdx.x * blockDim.x + threadIdx.x;
  if (idx >= N_NODES * D) return;
  int d = idx & (D - 1);
  float mu, rsig;
  bn_params(acc, d, mu, rsig);
  o[idx] = (p[idx] + q[idx] - mu) * rsig * g[d] + b[d];
}

// h = hloc + bn(x+hraw); writes fp32 + bf16
__global__ void bnadd_k(const float* __restrict__ x, const float* __restrict__ hraw,
                        const float* __restrict__ acc, const float* __restrict__ g,
                        const float* __restrict__ b, const float* __restrict__ hloc,
                        float* __restrict__ of, bf16* __restrict__ ob) {
  int idx = blockIdx.x * blockDim.x + threadIdx.x;
  if (idx >= N_NODES * D) return;
  int d = idx & (D - 1);
  float mu, rsig;
  bn_params(acc, d, mu, rsig);
  float v = hloc[idx] + (x[idx] + hraw[idx] - mu) * rsig * g[d] + b[d];
  of[idx] = v;
  ob[idx] = __float2bfloat16(v);
}

// ---------------- chunked selective scan -----------------------------------
__global__ __launch_bounds__(512) void scanA_k(const bf16* __restrict__ dt,
                                               const bf16* __restrict__ xs,
                                               const float* __restrict__ dbc,
                                               const float* __restrict__ Alog,
                                               float* __restrict__ Q,
                                               float* __restrict__ dtsum, int e0) {
  const int z = blockIdx.y;
  dt += (size_t)z * N_NODES * D;
  xs += (size_t)z * N_NODES * D;
  dbc += (size_t)z * N_NODES * 64;
  Alog += (size_t)(e0 + z) * D * DSTATE;
  Q += (size_t)z * NCHUNK * D * DSTATE;
  dtsum += (size_t)z * NCHUNK * D;
  int c = blockIdx.x;
  int d = threadIdx.x;
  float As[DSTATE], h[DSTATE];
#pragma unroll
  for (int s = 0; s < DSTATE; ++s) {
    As[s] = -__expf(Alog[d * DSTATE + s]);
    h[s] = 0.f;
  }
  float dts = 0.f;
  int t0 = c * LCHUNK;
  for (int t = t0; t < t0 + LCHUNK; ++t) {
    float dtv = __bfloat162float(dt[(size_t)t * D + d]);
    float xv = __bfloat162float(xs[(size_t)t * D + d]);
    float bx = dtv * xv;
    dts += dtv;
#pragma unroll
    for (int s = 0; s < DSTATE; ++s) {
      float Bv = dbc[(size_t)t * 64 + DTRANK + s];
      h[s] = fmaf(__expf(dtv * As[s]), h[s], bx * Bv);
    }
  }
  size_t base = ((size_t)c * D + d) * DSTATE;
#pragma unroll
  for (int s = 0; s < DSTATE; ++s) Q[base + s] = h[s];
  dtsum[c * D + d] = dts;
}

__global__ __launch_bounds__(256) void scanB_k(const float* __restrict__ Q,
                                               const float* __restrict__ dtsum,
                                               const float* __restrict__ Alog,
                                               float* __restrict__ Hin, int e0) {
  const int z = blockIdx.y;
  Q += (size_t)z * NCHUNK * D * DSTATE;
  dtsum += (size_t)z * NCHUNK * D;
  Alog += (size_t)(e0 + z) * D * DSTATE;
  Hin += (size_t)z * NCHUNK * D * DSTATE;
  int idx = blockIdx.x * blockDim.x + threadIdx.x;  // d*DSTATE + s
  int d = idx >> 4;
  float As = -__expf(Alog[idx]);
  float h = 0.f;
  for (int c = 0; c < NCHUNK; ++c) {
    size_t base = (size_t)c * D * DSTATE + idx;
    Hin[base] = h;
    h = fmaf(__expf(As * dtsum[c * D + d]), h, Q[base]);
  }
}

// writes gate-scaled u into concat layout: u[t*2048 + (e0+z)*512 + d]
__global__ __launch_bounds__(512) void scanC_k(const bf16* __restrict__ dt,
                                               const bf16* __restrict__ xs,
                                               const float* __restrict__ dbc,
                                               const float* __restrict__ Alog,
                                               const float* __restrict__ Hin,
                                               const bf16* __restrict__ xz,
                                               const float* __restrict__ Dp,
                                               const float* __restrict__ gate,
                                               bf16* __restrict__ u, int e0) {
  const int z = blockIdx.y;
  dt += (size_t)z * N_NODES * D;
  xs += (size_t)z * N_NODES * D;
  dbc += (size_t)z * N_NODES * 64;
  Alog += (size_t)(e0 + z) * D * DSTATE;
  Hin += (size_t)z * NCHUNK * D * DSTATE;
  xz += (size_t)z * N_NODES * 2 * D;
  Dp += (size_t)(e0 + z) * D;
  u += (size_t)(e0 + z) * 512;
  const int ge = e0 + z;
  int c = blockIdx.x;
  int d = threadIdx.x;
  float As[DSTATE], h[DSTATE];
  size_t base = ((size_t)c * D + d) * DSTATE;
#pragma unroll
  for (int s = 0; s < DSTATE; ++s) {
    As[s] = -__expf(Alog[d * DSTATE + s]);
    h[s] = Hin[base + s];
  }
  float Dv = Dp[d];
  int t0 = c * LCHUNK;
  for (int t = t0; t < t0 + LCHUNK; ++t) {
    float dtv = __bfloat162float(dt[(size_t)t * D + d]);
    float xv = __bfloat162float(xs[(size_t)t * D + d]);
    float bx = dtv * xv;
    float y = 0.f;
#pragma unroll
    for (int s = 0; s < DSTATE; ++s) {
      float Bv = dbc[(size_t)t * 64 + DTRANK + s];
      float Cv = dbc[(size_t)t * 64 + DTRANK + DSTATE + s];
      h[s] = fmaf(__expf(dtv * As[s]), h[s], bx * Bv);
      y = fmaf(h[s], Cv, y);
    }
    float zv = __bfloat162float(xz[(size_t)t * (2 * D) + D + d]);
    float gv = gate[t * NEXP + ge];
    u[(size_t)t * 2048 + d] = __float2bfloat16(gv * (y + Dv * xv) * siluf(zv));
  }
}

extern "C" void kernel_launch(void* const* d_in, const int* in_sizes, int n_in,
                              void* d_out, int out_size, void* d_ws, size_t ws_size,
                              hipStream_t stream) {
  const float* x = (const float*)d_in[0];
  const int* ei = (const int*)d_in[1];
  const float* ea = (const float*)d_in[2];
  const float* gin_w1 = (const float*)d_in[3];
  const float* gin_b1 = (const float*)d_in[4];
  const float* gin_w2 = (const float*)d_in[5];
  const float* gin_b2 = (const float*)d_in[6];
  const float* bn1l_g = (const float*)d_in[7];
  const float* bn1l_b = (const float*)d_in[8];
  const float* bn1a_g = (const float*)d_in[9];
  const float* bn1a_b = (const float*)d_in[10];
  const float* bn2_g = (const float*)d_in[11];
  const float* bn2_b = (const float*)d_in[12];
  const float* gate_w1 = (const float*)d_in[13];
  const float* gate_b1 = (const float*)d_in[14];
  const float* gate_w2 = (const float*)d_in[15];
  const float* gate_b2 = (const float*)d_in[16];
  const float* in_w = (const float*)d_in[17];
  const float* conv_w = (const float*)d_in[18];
  const float* conv_b = (const float*)d_in[19];
  const float* x_w = (const float*)d_in[20];
  const float* dt_w = (const float*)d_in[21];
  const float* dt_b = (const float*)d_in[22];
  const float* A_log = (const float*)d_in[23];
  const float* Dp = (const float*)d_in[24];
  const float* out_w = (const float*)d_in[25];
  const float* ff_w1 = (const float*)d_in[26];
  const float* ff_b1 = (const float*)d_in[27];
  const float* ff_w2 = (const float*)d_in[28];
  const float* ff_b2 = (const float*)d_in[29];
  float* out = (float*)d_out;

  const size_t ND = (size_t)N_NODES * D;  // 2M elems
  const size_t NDb = ND / 2;              // bf16 buffer in float units

  const size_t fixed_f = 3 * ND + (size_t)N_NODES * 256 + 16384 + 2490624 + ND + 2048 +
                         81920 + 2 * ND + 4096;
  const size_t per_f = 2 * ND + NDb + (size_t)N_NODES * 64 + NDb +
                       2 * (size_t)NCHUNK * D * DSTATE + (size_t)NCHUNK * D;
  const int EB = (ws_size >= (fixed_f + 4 * per_f + 65536) * sizeof(float)) ? 4 : 1;

  float* ws = (float*)d_ws;
  size_t off = 0;
  auto alloc = [&](size_t n) {
    float* p = ws + off;
    off += (n + 63) & ~(size_t)63;
    return p;
  };
  float* ffo = alloc(ND);
  float* pbuf = alloc(ND);     // hpre_bf + t1_bf; later: ffh_bf
  float* hlocal = alloc(ND);   // gin raw -> normed in place
  float* g1 = alloc((size_t)N_NODES * 256);
  float* gate = alloc((size_t)N_NODES * NEXP);
  bf16* gw1t = (bf16*)alloc(131072);
  bf16* gw2t = (bf16*)alloc(131072);
  bf16* gatew1t = (bf16*)alloc(65536);
  bf16* inwt = (bf16*)alloc(1048576);
  bf16* xwt = (bf16*)alloc(65536);
  bf16* outwt_cat = (bf16*)alloc(524288);  // [512][2048] bf16
  bf16* ffw1t = (bf16*)alloc(262144);
  bf16* ffw2t = (bf16*)alloc(262144);
  // zero-region: deg, cnt, accs contiguous (single memset)
  int* deg = (int*)alloc(N_NODES);
  int* cnt = (int*)alloc(N_NODES);
  float* accs = alloc(3072);  // acc1 | acc2 | acc3
  int* eid = (int*)alloc(E_EDGE);
  int* rowstart = (int*)alloc(N_NODES);
  float* xbf_f = alloc(NDb);
  float* xz_f = alloc((size_t)EB * ND);    // bf16 xz; later: hcomb fp32
  float* xs_f = alloc((size_t)EB * NDb);
  float* dbc = alloc((size_t)EB * N_NODES * 64);
  float* dtb_f = alloc((size_t)EB * NDb);
  float* Qb = alloc((size_t)EB * NCHUNK * D * DSTATE);
  float* Hin = alloc((size_t)EB * NCHUNK * D * DSTATE);
  float* dtsum = alloc((size_t)EB * NCHUNK * D);
  float* ucat_f = alloc(4 * NDb);  // 4096x2048 bf16 always full; later: hcomb_bf
  float* hattn_raw = alloc(ND);
  float* acc1 = accs, *acc2 = accs + 1024, *acc3 = accs + 2048;

  bf16* x_bf = (bf16*)xbf_f;
  bf16* hpre_bf = (bf16*)pbuf;
  bf16* t1_bf = (bf16*)(pbuf + NDb);
  bf16* xz_bf = (bf16*)xz_f;
  bf16* xs_bf = (bf16*)xs_f;
  bf16* dt_bf = (bf16*)dtb_f;
  bf16* ucat = (bf16*)ucat_f;
  // phase-4 aliases (source buffers dead by then)
  float* hcomb = xz_f;
  bf16* hcomb_bf = (bf16*)(ucat_f);   // ucat dead after concat GEMM... but bnadd runs after it
  bf16* ffh_bf = (bf16*)pbuf;

  const int nelem = N_NODES * D;
  const int ew = (nelem + 255) / 256;

  // single zero pass: deg + cnt + accs (contiguous, 64-aligned sizes)
  hipMemsetAsync(deg, 0, (N_NODES + N_NODES + 3072) * sizeof(float), stream);

  // ---- weight transposes ----
  wtrans_k<<<dim3(16, 16, 1), 256, 0, stream>>>(gin_w1, gw1t, 512, 512, 512, 0, 0);
  wtrans_k<<<dim3(16, 16, 1), 256, 0, stream>>>(gin_w2, gw2t, 512, 512, 512, 0, 0);
  wtrans_k<<<dim3(8, 16, 1), 256, 0, stream>>>(gate_w1, gatew1t, 512, 256, 512, 0, 0);
  wtrans_k<<<dim3(32, 16, 4), 256, 0, stream>>>(in_w, inwt, 512, 1024, 512,
                                                (long)512 * 1024, (long)512 * 1024);
  wtrans_k<<<dim3(2, 16, 4), 256, 0, stream>>>(x_w, xwt, 512, 64, 512, (long)512 * 64,
                                               (long)64 * 512);
  // out_w -> concat columns: expert e occupies cols [e*512, e*512+512), row stride 2048
  wtrans_k<<<dim3(16, 16, 4), 256, 0, stream>>>(out_w, outwt_cat, 512, 512, 2048,
                                                (long)512 * 512, (long)512);
  wtrans_k<<<dim3(32, 16, 1), 256, 0, stream>>>(ff_w1, ffw1t, 512, 1024, 512, 0, 0);
  wtrans_k<<<dim3(16, 32, 1), 256, 0, stream>>>(ff_w2, ffw2t, 1024, 512, 1024, 0, 0);

  // ---- CSR build + GIN local branch ----
  hist_k<<<E_EDGE / 256, 256, 0, stream>>>(ei, deg);
  prefix_k<<<1, 1024, 0, stream>>>(deg, rowstart);
  scatter_k<<<E_EDGE / 256, 256, 0, stream>>>(ei, rowstart, cnt, eid);
  aggr_gather_k<<<N_NODES, 256, 0, stream>>>(x, ei, ea, rowstart, deg, eid, hpre_bf, x_bf);
  mm_k<2, 1><<<dim3(8, 32, 1), 256, 0, stream>>>(hpre_bf, 512, 0, gw1t, 512, 0, gin_b1,
                                                 nullptr, t1_bf, 512, 0, 512);
  mm_k<2, 0><<<dim3(8, 32, 1), 256, 0, stream>>>(t1_bf, 512, 0, gw2t, 512, 0, gin_b2,
                                                 hlocal, nullptr, 512, 0, 512);
  colstats_k<<<64, 256, 0, stream>>>(x, hlocal, acc1);
  norm_k<<<ew, 256, 0, stream>>>(x, hlocal, acc1, bn1l_g, bn1l_b, hlocal);

  // ---- gate ----
  mm_k<2, 1><<<dim3(4, 32, 1), 256, 0, stream>>>(x_bf, 512, 0, gatew1t, 512, 0, gate_b1,
                                                 g1, nullptr, 256, 0, 512);
  gate2_k<<<N_NODES / 4, 256, 0, stream>>>(g1, gate_w2, gate_b2, gate);

  // ---- experts (z-batched by EB); scanC writes gate-scaled concat u ----
  for (int e0 = 0; e0 < NEXP; e0 += EB) {
    mm_k<4, 0><<<dim3(8, 32, EB), 256, 0, stream>>>(
        x_bf, 512, 0, inwt + (size_t)e0 * 512 * 1024, 512, (long)512 * 1024, nullptr,
        nullptr, xz_bf, 1024, (long)N_NODES * 1024, 512);
    conv_silu_k<<<dim3(ew, EB), 256, 0, stream>>>(xz_bf, conv_w, conv_b, xs_bf, e0);
    mm_k<2, 0><<<dim3(1, 32, EB), 256, 0, stream>>>(
        xs_bf, 512, (long)ND, xwt + (size_t)e0 * 64 * 512, 512, (long)64 * 512, nullptr,
        dbc, nullptr, 64, (long)N_NODES * 64, 512);
    dt_k<<<dim3(ew, EB), 256, 0, stream>>>(dbc, dt_w, dt_b, dt_bf, e0);
    scanA_k<<<dim3(NCHUNK, EB), 512, 0, stream>>>(dt_bf, xs_bf, dbc, A_log, Qb, dtsum, e0);
    scanB_k<<<dim3((D * DSTATE) / 256, EB), 256, 0, stream>>>(Qb, dtsum, A_log, Hin, e0);
    scanC_k<<<dim3(NCHUNK, EB), 512, 0, stream>>>(dt_bf, xs_bf, dbc, A_log, Hin, xz_bf, Dp,
                                                  gate, ucat, e0);
  }
  // single concat out_proj: hattn_raw = ucat[4096x2048] @ outwt_cat^T
  mm_k<2, 0><<<dim3(8, 32, 1), 256, 0, stream>>>(ucat, 2048, 0, outwt_cat, 2048, 0,
                                                 nullptr, hattn_raw, nullptr, 512, 0, 2048);

  // ---- attn BN (+add hlocal) fused, FFN, final BN ----
  colstats_k<<<64, 256, 0, stream>>>(x, hattn_raw, acc2);
  bnadd_k<<<ew, 256, 0, stream>>>(x, hattn_raw, acc2, bn1a_g, bn1a_b, hlocal, hcomb,
                                  hcomb_bf);
  mm_k<4, 1><<<dim3(8, 32, 1), 256, 0, stream>>>(hcomb_bf, 512, 0, ffw1t, 512, 0, ff_b1,
                                                 nullptr, ffh_bf, 1024, 0, 512);
  mm_k<2, 0><<<dim3(8, 32, 1), 256, 0, stream>>>(ffh_bf, 1024, 0, ffw2t, 1024, 0, ff_b2,
                                                 ffo, nullptr, 512, 0, 1024);
  colstats_k<<<64, 256, 0, stream>>>(hcomb, ffo, acc3);
  norm_k<<<ew, 256, 0, stream>>>(hcomb, ffo, acc3, bn2_g, bn2_b, out);
}

// Round 8
// 460.023 us; speedup vs baseline: 4.6167x; 1.0736x over previous
//
#include <hip/hip_runtime.h>
#include <hip/hip_bf16.h>
#include <math.h>

#define N_NODES 4096
#define E_EDGE 65536
#define D 512
#define NEXP 4
#define DSTATE 16
#define DCONV 4
#define DTRANK 32
#define EPS 1e-5f
#define LCHUNK 32
#define NCHUNK (N_NODES / LCHUNK)

typedef __hip_bfloat16 bf16;
typedef short bf16x8 __attribute__((ext_vector_type(8)));
typedef float f32x4 __attribute__((ext_vector_type(4)));
typedef unsigned short u16x4 __attribute__((ext_vector_type(4)));

__device__ __forceinline__ float siluf(float x) { return x / (1.f + __expf(-x)); }
__device__ __forceinline__ float softplusf(float x) {
  return (x > 20.f) ? x : log1pf(__expf(x));
}
__device__ __forceinline__ unsigned short f2bf(float v) {
  bf16 b = __float2bfloat16(v);
  return *reinterpret_cast<unsigned short*>(&b);
}

// async global->LDS, 16B per lane; lds dest must be wave-uniform base (HW adds lane*16)
__device__ __forceinline__ void gload16(const void* g, void* l) {
  __builtin_amdgcn_global_load_lds(
      (const __attribute__((address_space(1))) void*)g,
      (__attribute__((address_space(3))) void*)l, 16, 0, 0);
}

// ---------------- MFMA bf16 GEMM ------------------------------------------
// C(MxN) = A(MxK) @ Bt(NxK)^T. A,Bt bf16 row-major (lda/ldb elems, both %8==0).
// BM=128, BN=FN*32, 256 thr = 4 waves (2x2), wave tile 64 x FN*16, BK=32.
// Operand-SWAPPED mfma: lane owns row m=l&15, cols n=(l>>4)*4..+3 -> vector stores.
// EPI 0: C=A@B(+bias); EPI 1: relu(+bias).
template <int FN, int EPI>
__global__ __launch_bounds__(256, 2) void mm_k(
    const bf16* __restrict__ A, int lda, long sA,
    const bf16* __restrict__ Bt, int ldb, long sB,
    const float* __restrict__ bias,
    float* __restrict__ Cf, bf16* __restrict__ Cb, int ldc, long sC, int K) {
  constexpr int BN = FN * 32;
  __shared__ __align__(16) bf16 As[128 * 32];
  __shared__ __align__(16) bf16 Bs[BN * 32];
  const int z = blockIdx.z;
  A += (size_t)z * sA;
  Bt += (size_t)z * sB;
  const int tid = threadIdx.x;
  const int w = tid >> 6, l = tid & 63;
  const int wr = w >> 1, wc = w & 1;
  const int bm = blockIdx.y * 128, bn = blockIdx.x * BN;

  f32x4 acc[4][FN];
#pragma unroll
  for (int i = 0; i < 4; ++i)
#pragma unroll
    for (int j = 0; j < FN; ++j) acc[i][j] = 0.f;

  const int srow = l >> 2, schunk = l & 3;
  const bf16* gA = A + (size_t)(bm + w * 16 + srow) * lda + schunk * 8;
  const bf16* gB = Bt + (size_t)(bn + w * 16 + srow) * ldb + schunk * 8;
  bf16* lA = As + w * 512;
  bf16* lB = Bs + w * 512;

  const int ar = wr * 64 + (l & 15);
  const int br = wc * FN * 16 + (l & 15);
  const int kb = l >> 4;

  for (int k0 = 0; k0 < K; k0 += 32) {
    gload16(gA + k0, lA);
    gload16(gA + k0 + (size_t)64 * lda, lA + 64 * 32);
    gload16(gB + k0, lB);
    if (FN == 4) gload16(gB + k0 + (size_t)64 * ldb, lB + 64 * 32);
    __syncthreads();
    const bf16x8* Ap = (const bf16x8*)As;
    const bf16x8* Bp = (const bf16x8*)Bs;
    bf16x8 af[4], bfr[FN];
#pragma unroll
    for (int i = 0; i < 4; ++i) af[i] = Ap[(ar + i * 16) * 4 + kb];
#pragma unroll
    for (int j = 0; j < FN; ++j) bfr[j] = Bp[(br + j * 16) * 4 + kb];
#pragma unroll
    for (int i = 0; i < 4; ++i)
#pragma unroll
      for (int j = 0; j < FN; ++j)
        acc[i][j] = __builtin_amdgcn_mfma_f32_16x16x32_bf16(bfr[j], af[i], acc[i][j], 0, 0, 0);
    __syncthreads();
  }

  if (Cf) Cf += (size_t)z * sC;
  if (Cb) Cb += (size_t)z * sC;
  const int r0 = bm + wr * 64 + (l & 15);
  const int cb0 = bn + wc * FN * 16 + ((l >> 4) << 2);
#pragma unroll
  for (int i = 0; i < 4; ++i) {
    const int row = r0 + i * 16;
#pragma unroll
    for (int j = 0; j < FN; ++j) {
      const int col = cb0 + j * 16;
      f32x4 v = acc[i][j];
      if (bias) v += *(const f32x4*)&bias[col];
      if (EPI == 1) {
#pragma unroll
        for (int r = 0; r < 4; ++r) v[r] = fmaxf(v[r], 0.f);
      }
      if (Cf) *(f32x4*)&Cf[(size_t)row * ldc + col] = v;
      if (Cb) {
        u16x4 u;
#pragma unroll
        for (int r = 0; r < 4; ++r) u[r] = f2bf(v[r]);
        *(u16x4*)&Cb[(size_t)row * ldc + col] = u;
      }
    }
  }
}

// -------- batched weight transpose+convert: in[K][N] f32 -> out[N][K] bf16 --
struct WtArgs {
  const float* in[8];
  bf16* out[8];
  int K[8], N[8], ldo[8];
  long sin[8], sout[8];
  int cum[8];  // exclusive-end cumulative block counts
};
__global__ __launch_bounds__(256) void wtrans_all_k(WtArgs a) {
  __shared__ float t[32][33];
  int b = blockIdx.x;
  int i = 0;
  while (b >= a.cum[i]) ++i;
  int local = b - (i ? a.cum[i - 1] : 0);
  const int ntx = a.N[i] / 32;
  const int nty = a.K[i] / 32;
  const int perz = ntx * nty;
  const int z = local / perz;
  const int rem = local - z * perz;
  const int bx = rem % ntx, by = rem / ntx;
  const float* in = a.in[i] + (size_t)z * a.sin[i];
  bf16* out = a.out[i] + (size_t)z * a.sout[i];
  const int N = a.N[i], ldo = a.ldo[i];
  const int n0 = bx * 32, k0 = by * 32;
  const int tx = threadIdx.x & 31, ty = threadIdx.x >> 5;
  for (int r = ty; r < 32; r += 8) t[r][tx] = in[(size_t)(k0 + r) * N + n0 + tx];
  __syncthreads();
  for (int r = ty; r < 32; r += 8)
    out[(size_t)(n0 + r) * ldo + k0 + tx] = __float2bfloat16(t[tx][r]);
}

// ---------------- CSR build: histogram, prefix scan, scatter ---------------
__global__ void hist_k(const int* __restrict__ ei, int* __restrict__ deg) {
  int e = blockIdx.x * 256 + threadIdx.x;
  if (e < E_EDGE) atomicAdd(&deg[ei[E_EDGE + e]], 1);
}

__global__ __launch_bounds__(1024) void prefix_k(const int* __restrict__ deg,
                                                 int* __restrict__ rowstart) {
  __shared__ int s[1024];
  int t = threadIdx.x;
  int base = t * 4;
  int d0 = deg[base], d1 = deg[base + 1], d2 = deg[base + 2], d3 = deg[base + 3];
  int sum = d0 + d1 + d2 + d3;
  s[t] = sum;
  __syncthreads();
  for (int off = 1; off < 1024; off <<= 1) {
    int v = (t >= off) ? s[t - off] : 0;
    __syncthreads();
    s[t] += v;
    __syncthreads();
  }
  int excl = s[t] - sum;
  rowstart[base] = excl;
  rowstart[base + 1] = excl + d0;
  rowstart[base + 2] = excl + d0 + d1;
  rowstart[base + 3] = excl + d0 + d1 + d2;
}

__global__ void scatter_k(const int* __restrict__ ei, const int* __restrict__ rowstart,
                          int* __restrict__ cnt, int* __restrict__ eid) {
  int e = blockIdx.x * 256 + threadIdx.x;
  if (e < E_EDGE) {
    int dst = ei[E_EDGE + e];
    int slot = rowstart[dst] + atomicAdd(&cnt[dst], 1);
    eid[slot] = e;
  }
}

// gather: per-node sum of relu(x[src]+ea[e]); writes hpre_bf and x_bf
__global__ __launch_bounds__(256) void aggr_gather_k(
    const float* __restrict__ x, const int* __restrict__ ei, const float* __restrict__ ea,
    const int* __restrict__ rowstart, const int* __restrict__ deg,
    const int* __restrict__ eid, bf16* __restrict__ hpre, bf16* __restrict__ xbf) {
  int n = blockIdx.x;
  int tid = threadIdx.x;
  int beg = rowstart[n];
  int end = beg + deg[n];
  float a0 = 0.f, a1 = 0.f;
  int i = beg;
  for (; i + 1 < end; i += 2) {
    int e0 = eid[i], e1 = eid[i + 1];
    int s0 = ei[e0], s1 = ei[e1];
    const float* x0 = x + (size_t)s0 * D;
    const float* e0p = ea + (size_t)e0 * D;
    const float* x1 = x + (size_t)s1 * D;
    const float* e1p = ea + (size_t)e1 * D;
    a0 += fmaxf(x0[tid] + e0p[tid], 0.f) + fmaxf(x1[tid] + e1p[tid], 0.f);
    a1 += fmaxf(x0[tid + 256] + e0p[tid + 256], 0.f) +
          fmaxf(x1[tid + 256] + e1p[tid + 256], 0.f);
  }
  if (i < end) {
    int e0 = eid[i];
    int s0 = ei[e0];
    const float* x0 = x + (size_t)s0 * D;
    const float* e0p = ea + (size_t)e0 * D;
    a0 += fmaxf(x0[tid] + e0p[tid], 0.f);
    a1 += fmaxf(x0[tid + 256] + e0p[tid + 256], 0.f);
  }
  float xv0 = x[(size_t)n * D + tid];
  float xv1 = x[(size_t)n * D + tid + 256];
  hpre[(size_t)n * D + tid] = __float2bfloat16(xv0 + a0);
  hpre[(size_t)n * D + tid + 256] = __float2bfloat16(xv1 + a1);
  xbf[(size_t)n * D + tid] = __float2bfloat16(xv0);
  xbf[(size_t)n * D + tid + 256] = __float2bfloat16(xv1);
}

// ---------------- gate second layer + softmax ------------------------------
__global__ __launch_bounds__(256) void gate2_k(const float* __restrict__ g1,
                                               const float* __restrict__ w2,
                                               const float* __restrict__ b2,
                                               float* __restrict__ gate) {
  int row = blockIdx.x * 4 + (threadIdx.x >> 6);
  int lane = threadIdx.x & 63;
  float a0 = 0.f, a1 = 0.f, a2 = 0.f, a3 = 0.f;
  for (int k = lane; k < 256; k += 64) {
    float v = g1[(size_t)row * 256 + k];
    a0 = fmaf(v, w2[k * 4 + 0], a0);
    a1 = fmaf(v, w2[k * 4 + 1], a1);
    a2 = fmaf(v, w2[k * 4 + 2], a2);
    a3 = fmaf(v, w2[k * 4 + 3], a3);
  }
#pragma unroll
  for (int off = 32; off; off >>= 1) {
    a0 += __shfl_down(a0, off);
    a1 += __shfl_down(a1, off);
    a2 += __shfl_down(a2, off);
    a3 += __shfl_down(a3, off);
  }
  if (lane == 0) {
    float l0 = a0 + b2[0], l1 = a1 + b2[1], l2 = a2 + b2[2], l3 = a3 + b2[3];
    float m = fmaxf(fmaxf(l0, l1), fmaxf(l2, l3));
    float e0 = __expf(l0 - m), e1 = __expf(l1 - m), e2 = __expf(l2 - m), e3 = __expf(l3 - m);
    float s = 1.f / (e0 + e1 + e2 + e3);
    gate[row * 4 + 0] = e0 * s;
    gate[row * 4 + 1] = e1 * s;
    gate[row * 4 + 2] = e2 * s;
    gate[row * 4 + 3] = e3 * s;
  }
}

// ---------------- causal depthwise conv + silu -> bf16 (xz is bf16) --------
__global__ void conv_silu_k(const bf16* __restrict__ xz, const float* __restrict__ cw,
                            const float* __restrict__ cb, bf16* __restrict__ xs, int e0) {
  const int z = blockIdx.y;
  xz += (size_t)z * N_NODES * 2 * D;
  xs += (size_t)z * N_NODES * D;
  cw += (size_t)(e0 + z) * D * DCONV;
  cb += (size_t)(e0 + z) * D;
  int idx = blockIdx.x * blockDim.x + threadIdx.x;
  if (idx >= N_NODES * D) return;
  int t = idx >> 9;
  int d = idx & (D - 1);
  float acc = cb[d];
#pragma unroll
  for (int k = 0; k < DCONV; ++k) {
    int tt = t + k - (DCONV - 1);
    if (tt >= 0)
      acc = fmaf(cw[d * DCONV + k], __bfloat162float(xz[(size_t)tt * (2 * D) + d]), acc);
  }
  xs[idx] = __float2bfloat16(siluf(acc));
}

// ---------------- fused dt: softplus(dbc[:, :32] @ dt_w + dt_b) -> bf16 ----
__global__ void dt_k(const float* __restrict__ dbc, const float* __restrict__ dtw,
                     const float* __restrict__ dtbias, bf16* __restrict__ dt, int e0) {
  const int z = blockIdx.y;
  dbc += (size_t)z * N_NODES * 64;
  dt += (size_t)z * N_NODES * D;
  dtw += (size_t)(e0 + z) * DTRANK * D;
  dtbias += (size_t)(e0 + z) * D;
  int idx = blockIdx.x * blockDim.x + threadIdx.x;
  int t = idx >> 9, d = idx & (D - 1);
  float acc = dtbias[d];
#pragma unroll
  for (int k = 0; k < DTRANK; ++k) acc = fmaf(dbc[t * 64 + k], dtw[k * D + d], acc);
  dt[idx] = __float2bfloat16(softplusf(acc));
}

// ------- column stats (1 input pair): acc[d] += sum, acc[512+d] += sumsq ----
__global__ __launch_bounds__(256) void colstats_k(const float* __restrict__ p,
                                                  const float* __restrict__ q,
                                                  float* __restrict__ acc) {
  __shared__ float sb[4][512], sb2[4][512];
  const int w = threadIdx.x >> 6, l = threadIdx.x & 63;
  float s[8], s2[8];
#pragma unroll
  for (int i = 0; i < 8; ++i) { s[i] = 0.f; s2[i] = 0.f; }
  for (int j = 0; j < 16; ++j) {
    size_t base = ((size_t)blockIdx.x * 64 + w * 16 + j) * D;
#pragma unroll
    for (int i = 0; i < 8; ++i) {
      int c = i * 64 + l;
      float v = p[base + c] + q[base + c];
      s[i] += v;
      s2[i] = fmaf(v, v, s2[i]);
    }
  }
#pragma unroll
  for (int i = 0; i < 8; ++i) {
    sb[w][i * 64 + l] = s[i];
    sb2[w][i * 64 + l] = s2[i];
  }
  __syncthreads();
  for (int c = threadIdx.x; c < 512; c += 256) {
    atomicAdd(&acc[c], sb[0][c] + sb[1][c] + sb[2][c] + sb[3][c]);
    atomicAdd(&acc[512 + c], sb2[0][c] + sb2[1][c] + sb2[2][c] + sb2[3][c]);
  }
}

// ------- fused dual column stats: acc1 over (x+p), acc2 over (x+q) ----------
__global__ __launch_bounds__(256) void colstats2_k(const float* __restrict__ x,
                                                   const float* __restrict__ p,
                                                   const float* __restrict__ q,
                                                   float* __restrict__ acc1,
                                                   float* __restrict__ acc2) {
  __shared__ float sb[4][512], sb2[4][512];
  const int w = threadIdx.x >> 6, l = threadIdx.x & 63;
  float s1[8], s1q[8], s2[8], s2q[8];
#pragma unroll
  for (int i = 0; i < 8; ++i) { s1[i] = 0.f; s1q[i] = 0.f; s2[i] = 0.f; s2q[i] = 0.f; }
  for (int j = 0; j < 16; ++j) {
    size_t base = ((size_t)blockIdx.x * 64 + w * 16 + j) * D;
#pragma unroll
    for (int i = 0; i < 8; ++i) {
      int c = i * 64 + l;
      float xv = x[base + c];
      float v1 = xv + p[base + c];
      float v2 = xv + q[base + c];
      s1[i] += v1;
      s1q[i] = fmaf(v1, v1, s1q[i]);
      s2[i] += v2;
      s2q[i] = fmaf(v2, v2, s2q[i]);
    }
  }
#pragma unroll
  for (int i = 0; i < 8; ++i) {
    sb[w][i * 64 + l] = s1[i];
    sb2[w][i * 64 + l] = s1q[i];
  }
  __syncthreads();
  for (int c = threadIdx.x; c < 512; c += 256) {
    atomicAdd(&acc1[c], sb[0][c] + sb[1][c] + sb[2][c] + sb[3][c]);
    atomicAdd(&acc1[512 + c], sb2[0][c] + sb2[1][c] + sb2[2][c] + sb2[3][c]);
  }
  __syncthreads();
#pragma unroll
  for (int i = 0; i < 8; ++i) {
    sb[w][i * 64 + l] = s2[i];
    sb2[w][i * 64 + l] = s2q[i];
  }
  __syncthreads();
  for (int c = threadIdx.x; c < 512; c += 256) {
    atomicAdd(&acc2[c], sb[0][c] + sb[1][c] + sb[2][c] + sb[3][c]);
    atomicAdd(&acc2[512 + c], sb2[0][c] + sb2[1][c] + sb2[2][c] + sb2[3][c]);
  }
}

__device__ __forceinline__ void bn_params(const float* acc, int d, float& mu, float& rsig) {
  mu = acc[d] * (1.f / N_NODES);
  float var = acc[512 + d] * (1.f / N_NODES) - mu * mu;
  rsig = rsqrtf(var + EPS);
}

// o = bn(p+q) (fp32)
__global__ void norm_k(const float* __restrict__ p, const float* __restrict__ q,
                       const float* __restrict__ acc, const float* __restrict__ g,
                       const float* __restrict__ b, float* __restrict__ o) {
  int idx = blockIdx.x * blockDim.x + threadIdx.x;
  if (idx >= N_NODES * D) return;
  int d = idx & (D - 1);
  float mu, rsig;
  bn_params(acc, d, mu, rsig);
  o[idx] = (p[idx] + q[idx] - mu) * rsig * g[d] + b[d];
}

// h = bn1l(x+hloc) + bn1a(x+hattn); writes fp32 + bf16
__global__ void bnadd2_k(const float* __restrict__ x, const float* __restrict__ hloc,
                         const float* __restrict__ hattn, const float* __restrict__ acc1,
                         const float* __restrict__ acc2, const float* __restrict__ g1,
                         const float* __restrict__ b1, const float* __restrict__ g2,
                         const float* __restrict__ b2, float* __restrict__ of,
                         bf16* __restrict__ ob) {
  int idx = blockIdx.x * blockDim.x + threadIdx.x;
  if (idx >= N_NODES * D) return;
  int d = idx & (D - 1);
  float mu1, rs1, mu2, rs2;
  bn_params(acc1, d, mu1, rs1);
  bn_params(acc2, d, mu2, rs2);
  float xv = x[idx];
  float v = (xv + hloc[idx] - mu1) * rs1 * g1[d] + b1[d] +
            (xv + hattn[idx] - mu2) * rs2 * g2[d] + b2[d];
  of[idx] = v;
  ob[idx] = __float2bfloat16(v);
}

// ---------------- chunked selective scan -----------------------------------
__global__ __launch_bounds__(512) void scanA_k(const bf16* __restrict__ dt,
                                               const bf16* __restrict__ xs,
                                               const float* __restrict__ dbc,
                                               const float* __restrict__ Alog,
                                               float* __restrict__ Q,
                                               float* __restrict__ dtsum, int e0) {
  const int z = blockIdx.y;
  dt += (size_t)z * N_NODES * D;
  xs += (size_t)z * N_NODES * D;
  dbc += (size_t)z * N_NODES * 64;
  Alog += (size_t)(e0 + z) * D * DSTATE;
  Q += (size_t)z * NCHUNK * D * DSTATE;
  dtsum += (size_t)z * NCHUNK * D;
  int c = blockIdx.x;
  int d = threadIdx.x;
  float As[DSTATE], h[DSTATE];
#pragma unroll
  for (int s = 0; s < DSTATE; ++s) {
    As[s] = -__expf(Alog[d * DSTATE + s]);
    h[s] = 0.f;
  }
  float dts = 0.f;
  int t0 = c * LCHUNK;
  for (int t = t0; t < t0 + LCHUNK; ++t) {
    float dtv = __bfloat162float(dt[(size_t)t * D + d]);
    float xv = __bfloat162float(xs[(size_t)t * D + d]);
    float bx = dtv * xv;
    dts += dtv;
#pragma unroll
    for (int s = 0; s < DSTATE; ++s) {
      float Bv = dbc[(size_t)t * 64 + DTRANK + s];
      h[s] = fmaf(__expf(dtv * As[s]), h[s], bx * Bv);
    }
  }
  size_t base = ((size_t)c * D + d) * DSTATE;
#pragma unroll
  for (int s = 0; s < DSTATE; ++s) Q[base + s] = h[s];
  dtsum[c * D + d] = dts;
}

__global__ __launch_bounds__(256) void scanB_k(const float* __restrict__ Q,
                                               const float* __restrict__ dtsum,
                                               const float* __restrict__ Alog,
                                               float* __restrict__ Hin, int e0) {
  const int z = blockIdx.y;
  Q += (size_t)z * NCHUNK * D * DSTATE;
  dtsum += (size_t)z * NCHUNK * D;
  Alog += (size_t)(e0 + z) * D * DSTATE;
  Hin += (size_t)z * NCHUNK * D * DSTATE;
  int idx = blockIdx.x * blockDim.x + threadIdx.x;  // d*DSTATE + s
  int d = idx >> 4;
  float As = -__expf(Alog[idx]);
  float h = 0.f;
  for (int c = 0; c < NCHUNK; ++c) {
    size_t base = (size_t)c * D * DSTATE + idx;
    Hin[base] = h;
    h = fmaf(__expf(As * dtsum[c * D + d]), h, Q[base]);
  }
}

// writes gate-scaled u into concat layout: u[t*2048 + (e0+z)*512 + d]
__global__ __launch_bounds__(512) void scanC_k(const bf16* __restrict__ dt,
                                               const bf16* __restrict__ xs,
                                               const float* __restrict__ dbc,
                                               const float* __restrict__ Alog,
                                               const float* __restrict__ Hin,
                                               const bf16* __restrict__ xz,
                                               const float* __restrict__ Dp,
                                               const float* __restrict__ gate,
                                               bf16* __restrict__ u, int e0) {
  const int z = blockIdx.y;
  dt += (size_t)z * N_NODES * D;
  xs += (size_t)z * N_NODES * D;
  dbc += (size_t)z * N_NODES * 64;
  Alog += (size_t)(e0 + z) * D * DSTATE;
  Hin += (size_t)z * NCHUNK * D * DSTATE;
  xz += (size_t)z * N_NODES * 2 * D;
  Dp += (size_t)(e0 + z) * D;
  u += (size_t)(e0 + z) * 512;
  const int ge = e0 + z;
  int c = blockIdx.x;
  int d = threadIdx.x;
  float As[DSTATE], h[DSTATE];
  size_t base = ((size_t)c * D + d) * DSTATE;
#pragma unroll
  for (int s = 0; s < DSTATE; ++s) {
    As[s] = -__expf(Alog[d * DSTATE + s]);
    h[s] = Hin[base + s];
  }
  float Dv = Dp[d];
  int t0 = c * LCHUNK;
  for (int t = t0; t < t0 + LCHUNK; ++t) {
    float dtv = __bfloat162float(dt[(size_t)t * D + d]);
    float xv = __bfloat162float(xs[(size_t)t * D + d]);
    float bx = dtv * xv;
    float y = 0.f;
#pragma unroll
    for (int s = 0; s < DSTATE; ++s) {
      float Bv = dbc[(size_t)t * 64 + DTRANK + s];
      float Cv = dbc[(size_t)t * 64 + DTRANK + DSTATE + s];
      h[s] = fmaf(__expf(dtv * As[s]), h[s], bx * Bv);
      y = fmaf(h[s], Cv, y);
    }
    float zv = __bfloat162float(xz[(size_t)t * (2 * D) + D + d]);
    float gv = gate[t * NEXP + ge];
    u[(size_t)t * 2048 + d] = __float2bfloat16(gv * (y + Dv * xv) * siluf(zv));
  }
}

extern "C" void kernel_launch(void* const* d_in, const int* in_sizes, int n_in,
                              void* d_out, int out_size, void* d_ws, size_t ws_size,
                              hipStream_t stream) {
  const float* x = (const float*)d_in[0];
  const int* ei = (const int*)d_in[1];
  const float* ea = (const float*)d_in[2];
  const float* gin_w1 = (const float*)d_in[3];
  const float* gin_b1 = (const float*)d_in[4];
  const float* gin_w2 = (const float*)d_in[5];
  const float* gin_b2 = (const float*)d_in[6];
  const float* bn1l_g = (const float*)d_in[7];
  const float* bn1l_b = (const float*)d_in[8];
  const float* bn1a_g = (const float*)d_in[9];
  const float* bn1a_b = (const float*)d_in[10];
  const float* bn2_g = (const float*)d_in[11];
  const float* bn2_b = (const float*)d_in[12];
  const float* gate_w1 = (const float*)d_in[13];
  const float* gate_b1 = (const float*)d_in[14];
  const float* gate_w2 = (const float*)d_in[15];
  const float* gate_b2 = (const float*)d_in[16];
  const float* in_w = (const float*)d_in[17];
  const float* conv_w = (const float*)d_in[18];
  const float* conv_b = (const float*)d_in[19];
  const float* x_w = (const float*)d_in[20];
  const float* dt_w = (const float*)d_in[21];
  const float* dt_b = (const float*)d_in[22];
  const float* A_log = (const float*)d_in[23];
  const float* Dp = (const float*)d_in[24];
  const float* out_w = (const float*)d_in[25];
  const float* ff_w1 = (const float*)d_in[26];
  const float* ff_b1 = (const float*)d_in[27];
  const float* ff_w2 = (const float*)d_in[28];
  const float* ff_b2 = (const float*)d_in[29];
  float* out = (float*)d_out;

  const size_t ND = (size_t)N_NODES * D;  // 2M elems
  const size_t NDb = ND / 2;              // bf16 buffer in float units

  const size_t fixed_f = 3 * ND + (size_t)N_NODES * 256 + 16384 + 2490624 + ND + 2048 +
                         81920 + 2 * ND + 4096;
  const size_t per_f = 2 * ND + NDb + (size_t)N_NODES * 64 + NDb +
                       2 * (size_t)NCHUNK * D * DSTATE + (size_t)NCHUNK * D;
  const int EB = (ws_size >= (fixed_f + 4 * per_f + 65536) * sizeof(float)) ? 4 : 1;

  float* ws = (float*)d_ws;
  size_t off = 0;
  auto alloc = [&](size_t n) {
    float* p = ws + off;
    off += (n + 63) & ~(size_t)63;
    return p;
  };
  float* ffo = alloc(ND);
  float* pbuf = alloc(ND);     // hpre_bf + t1_bf; later: ffh_bf
  float* hlocal = alloc(ND);   // gin raw (stays raw; both BNs fused in bnadd2)
  float* g1 = alloc((size_t)N_NODES * 256);
  float* gate = alloc((size_t)N_NODES * NEXP);
  bf16* gw1t = (bf16*)alloc(131072);
  bf16* gw2t = (bf16*)alloc(131072);
  bf16* gatew1t = (bf16*)alloc(65536);
  bf16* inwt = (bf16*)alloc(1048576);
  bf16* xwt = (bf16*)alloc(65536);
  bf16* outwt_cat = (bf16*)alloc(524288);  // [512][2048] bf16
  bf16* ffw1t = (bf16*)alloc(262144);
  bf16* ffw2t = (bf16*)alloc(262144);
  // zero-region: deg, cnt, accs contiguous (single memset)
  int* deg = (int*)alloc(N_NODES);
  int* cnt = (int*)alloc(N_NODES);
  float* accs = alloc(3072);  // acc1 | acc2 | acc3
  int* eid = (int*)alloc(E_EDGE);
  int* rowstart = (int*)alloc(N_NODES);
  float* xbf_f = alloc(NDb);
  float* xz_f = alloc((size_t)EB * ND);    // bf16 xz; later: hcomb fp32
  float* xs_f = alloc((size_t)EB * NDb);
  float* dbc = alloc((size_t)EB * N_NODES * 64);
  float* dtb_f = alloc((size_t)EB * NDb);
  float* Qb = alloc((size_t)EB * NCHUNK * D * DSTATE);
  float* Hin = alloc((size_t)EB * NCHUNK * D * DSTATE);
  float* dtsum = alloc((size_t)EB * NCHUNK * D);
  float* ucat_f = alloc(4 * NDb);  // 4096x2048 bf16; later: hcomb_bf
  float* hattn_raw = alloc(ND);
  float* acc1 = accs, *acc2 = accs + 1024, *acc3 = accs + 2048;

  bf16* x_bf = (bf16*)xbf_f;
  bf16* hpre_bf = (bf16*)pbuf;
  bf16* t1_bf = (bf16*)(pbuf + NDb);
  bf16* xz_bf = (bf16*)xz_f;
  bf16* xs_bf = (bf16*)xs_f;
  bf16* dt_bf = (bf16*)dtb_f;
  bf16* ucat = (bf16*)ucat_f;
  // phase-4 aliases (source buffers dead by then)
  float* hcomb = xz_f;
  bf16* hcomb_bf = (bf16*)(ucat_f);
  bf16* ffh_bf = (bf16*)pbuf;

  const int nelem = N_NODES * D;
  const int ew = (nelem + 255) / 256;

  // single zero pass: deg + cnt + accs (contiguous, 64-aligned sizes)
  hipMemsetAsync(deg, 0, (N_NODES + N_NODES + 3072) * sizeof(float), stream);

  // ---- batched weight transposes ----
  WtArgs wa;
  const float* wsrc[8] = {gin_w1, gin_w2, gate_w1, in_w, x_w, out_w, ff_w1, ff_w2};
  bf16* wdst[8] = {gw1t, gw2t, gatew1t, inwt, xwt, outwt_cat, ffw1t, ffw2t};
  int wK[8] = {512, 512, 512, 512, 512, 512, 512, 1024};
  int wN[8] = {512, 512, 256, 1024, 64, 512, 1024, 512};
  int wldo[8] = {512, 512, 512, 512, 512, 2048, 512, 1024};
  long wsin[8] = {0, 0, 0, (long)512 * 1024, (long)512 * 64, (long)512 * 512, 0, 0};
  long wsout[8] = {0, 0, 0, (long)512 * 1024, (long)64 * 512, 512, 0, 0};
  int wz[8] = {1, 1, 1, 4, 4, 4, 1, 1};
  int cum = 0;
  for (int i = 0; i < 8; ++i) {
    wa.in[i] = wsrc[i];
    wa.out[i] = wdst[i];
    wa.K[i] = wK[i];
    wa.N[i] = wN[i];
    wa.ldo[i] = wldo[i];
    wa.sin[i] = wsin[i];
    wa.sout[i] = wsout[i];
    cum += (wN[i] / 32) * (wK[i] / 32) * wz[i];
    wa.cum[i] = cum;
  }
  wtrans_all_k<<<cum, 256, 0, stream>>>(wa);

  // ---- CSR build + GIN local branch ----
  hist_k<<<E_EDGE / 256, 256, 0, stream>>>(ei, deg);
  prefix_k<<<1, 1024, 0, stream>>>(deg, rowstart);
  scatter_k<<<E_EDGE / 256, 256, 0, stream>>>(ei, rowstart, cnt, eid);
  aggr_gather_k<<<N_NODES, 256, 0, stream>>>(x, ei, ea, rowstart, deg, eid, hpre_bf, x_bf);
  mm_k<2, 1><<<dim3(8, 32, 1), 256, 0, stream>>>(hpre_bf, 512, 0, gw1t, 512, 0, gin_b1,
                                                 nullptr, t1_bf, 512, 0, 512);
  mm_k<2, 0><<<dim3(8, 32, 1), 256, 0, stream>>>(t1_bf, 512, 0, gw2t, 512, 0, gin_b2,
                                                 hlocal, nullptr, 512, 0, 512);

  // ---- gate ----
  mm_k<2, 1><<<dim3(4, 32, 1), 256, 0, stream>>>(x_bf, 512, 0, gatew1t, 512, 0, gate_b1,
                                                 g1, nullptr, 256, 0, 512);
  gate2_k<<<N_NODES / 4, 256, 0, stream>>>(g1, gate_w2, gate_b2, gate);

  // ---- experts (z-batched by EB); scanC writes gate-scaled concat u ----
  for (int e0 = 0; e0 < NEXP; e0 += EB) {
    mm_k<4, 0><<<dim3(8, 32, EB), 256, 0, stream>>>(
        x_bf, 512, 0, inwt + (size_t)e0 * 512 * 1024, 512, (long)512 * 1024, nullptr,
        nullptr, xz_bf, 1024, (long)N_NODES * 1024, 512);
    conv_silu_k<<<dim3(ew, EB), 256, 0, stream>>>(xz_bf, conv_w, conv_b, xs_bf, e0);
    mm_k<2, 0><<<dim3(1, 32, EB), 256, 0, stream>>>(
        xs_bf, 512, (long)ND, xwt + (size_t)e0 * 64 * 512, 512, (long)64 * 512, nullptr,
        dbc, nullptr, 64, (long)N_NODES * 64, 512);
    dt_k<<<dim3(ew, EB), 256, 0, stream>>>(dbc, dt_w, dt_b, dt_bf, e0);
    scanA_k<<<dim3(NCHUNK, EB), 512, 0, stream>>>(dt_bf, xs_bf, dbc, A_log, Qb, dtsum, e0);
    scanB_k<<<dim3((D * DSTATE) / 256, EB), 256, 0, stream>>>(Qb, dtsum, A_log, Hin, e0);
    scanC_k<<<dim3(NCHUNK, EB), 512, 0, stream>>>(dt_bf, xs_bf, dbc, A_log, Hin, xz_bf, Dp,
                                                  gate, ucat, e0);
  }
  // single concat out_proj: hattn_raw = ucat[4096x2048] @ outwt_cat^T
  mm_k<2, 0><<<dim3(8, 32, 1), 256, 0, stream>>>(ucat, 2048, 0, outwt_cat, 2048, 0,
                                                 nullptr, hattn_raw, nullptr, 512, 0, 2048);

  // ---- fused dual BN stats, dual-BN add, FFN, final BN ----
  colstats2_k<<<64, 256, 0, stream>>>(x, hlocal, hattn_raw, acc1, acc2);
  bnadd2_k<<<ew, 256, 0, stream>>>(x, hlocal, hattn_raw, acc1, acc2, bn1l_g, bn1l_b,
                                   bn1a_g, bn1a_b, hcomb, hcomb_bf);
  mm_k<4, 1><<<dim3(8, 32, 1), 256, 0, stream>>>(hcomb_bf, 512, 0, ffw1t, 512, 0, ff_b1,
                                                 nullptr, ffh_bf, 1024, 0, 512);
  mm_k<2, 0><<<dim3(8, 32, 1), 256, 0, stream>>>(ffh_bf, 1024, 0, ffw2t, 1024, 0, ff_b2,
                                                 ffo, nullptr, 512, 0, 1024);
  colstats_k<<<64, 256, 0, stream>>>(hcomb, ffo, acc3);
  norm_k<<<ew, 256, 0, stream>>>(hcomb, ffo, acc3, bn2_g, bn2_b, out);
}